// Round 12
// baseline (1429.995 us; speedup 1.0000x reference)
//
#include <hip/hip_runtime.h>
#include <math.h>

constexpr int N_TYPES = 4;
constexpr int N_REL   = 8;
constexpr int N_HEADS = 8;
constexpr int IN_DIM  = 256;
constexpr int N_HID   = 128;
constexpr int D_K     = 16;
constexpr int N_LAYERS= 2;
constexpr int NN      = 100000;
constexpr int NE      = 400000;
constexpr int NBLK    = (NN + 255) / 256;   // scan blocks

__device__ __forceinline__ float gelu_f(float x) {
    const float c = 0.7978845608028654f; // sqrt(2/pi)
    float x3 = x * x * x;
    return 0.5f * x * (1.0f + tanhf(c * (x + 0.044715f * x3)));
}
__device__ __forceinline__ float sigmoid_f(float x) {
    return 1.0f / (1.0f + expf(-x));
}

// ---------------- bucketing: nodes by type, edges by target ----------------
__global__ __launch_bounds__(256) void count2_kernel(
    const int* __restrict__ ntype, const int* __restrict__ tgt,
    unsigned* ncnt, unsigned* tcnt)
{
    int i = blockIdx.x * 256 + threadIdx.x;
    int lane = threadIdx.x & 63;
    int t = (i < NN) ? ntype[i] : -1;
    #pragma unroll
    for (int tt = 0; tt < N_TYPES; tt++) {
        unsigned long long m = __ballot(t == tt);
        if (m != 0ull && lane == __ffsll((unsigned long long)m) - 1)
            atomicAdd(&ncnt[tt], (unsigned)__popcll(m));
    }
    if (i < NE) atomicAdd(&tcnt[tgt[i]], 1u);
}

__global__ void node_offsets_kernel(unsigned* c)
{
    // layout: ncnt[0:4] ncur[4:8] noff[8:13]
    unsigned a = 0;
    for (int t = 0; t < N_TYPES; t++) { c[8 + t] = a; c[4 + t] = a; a += c[t]; }
    c[8 + N_TYPES] = a;
}

// hierarchical exclusive scan over tcnt[NN] -> eoff[NN+1]
__global__ __launch_bounds__(256) void scan1_kernel(
    const unsigned* __restrict__ cnt, unsigned* __restrict__ eoff,
    unsigned* __restrict__ bsum)
{
    __shared__ unsigned sh[256];
    int i = blockIdx.x * 256 + threadIdx.x;
    unsigned v = (i < NN) ? cnt[i] : 0u;
    sh[threadIdx.x] = v;
    __syncthreads();
    for (int off = 1; off < 256; off <<= 1) {
        unsigned add = (threadIdx.x >= off) ? sh[threadIdx.x - off] : 0u;
        __syncthreads();
        sh[threadIdx.x] += add;
        __syncthreads();
    }
    if (i < NN) eoff[i] = sh[threadIdx.x] - v;      // block-local exclusive
    if (threadIdx.x == 255) bsum[blockIdx.x] = sh[255];
}

__global__ __launch_bounds__(512) void scan2_kernel(unsigned* __restrict__ bsum)
{
    __shared__ unsigned sh[512];
    int i = threadIdx.x;
    unsigned v = (i < NBLK) ? bsum[i] : 0u;
    sh[i] = v;
    __syncthreads();
    for (int off = 1; off < 512; off <<= 1) {
        unsigned add = (i >= off) ? sh[i - off] : 0u;
        __syncthreads();
        sh[i] += add;
        __syncthreads();
    }
    if (i < NBLK) bsum[i] = sh[i] - v;              // exclusive block offsets
}

__global__ __launch_bounds__(256) void scan3_kernel(
    unsigned* __restrict__ eoff, const unsigned* __restrict__ bsum,
    unsigned* __restrict__ ecur)
{
    int i = blockIdx.x * 256 + threadIdx.x;
    if (i < NN) {
        unsigned v = eoff[i] + bsum[blockIdx.x];
        eoff[i] = v;
        ecur[i] = v;
    }
    if (i == 0) eoff[NN] = (unsigned)NE;
}

__global__ __launch_bounds__(256) void scatter2_kernel(
    const int* __restrict__ ntype,
    const int* __restrict__ src, const int* __restrict__ tgt,
    const int* __restrict__ etype,
    unsigned* ncur, unsigned* ecur,
    int* __restrict__ nidx,
    int* __restrict__ er_t)            // packed (src<<3) | rel
{
    int i = blockIdx.x * 256 + threadIdx.x;
    int lane = threadIdx.x & 63;
    int t = (i < NN) ? ntype[i] : -1;
    // wave-aggregated slot assignment: 1 atomic per (wave, type) not per node
    #pragma unroll
    for (int tt = 0; tt < N_TYPES; tt++) {
        unsigned long long m = __ballot(t == tt);
        if (m == 0ull) continue;
        int leader = __ffsll((unsigned long long)m) - 1;
        unsigned base = 0;
        if (lane == leader) base = atomicAdd(&ncur[tt], (unsigned)__popcll(m));
        base = __shfl(base, leader, 64);
        if (t == tt) {
            unsigned rank = (unsigned)__popcll(m & ((1ull << lane) - 1ull));
            nidx[base + rank] = i;
        }
    }
    if (i < NE) {
        int tg = tgt[i];
        unsigned p = atomicAdd(&ecur[tg], 1u);   // 100K distinct addrs, low contention
        er_t[p] = (src[i] << 3) | etype[i];
    }
}

// ---------------- per-type linear, 128x128 tile, 8x8 per thread, BK=32 ------
// MIN: 0 = plain input, 1 = gelu(input)
// MOUT: 0 = tanh(out), 1 = plain (+bias), 2 = skip-mix with hprev
// OS: output element stride (2 = interleaved kv buffer; out pre-offset by caller)
template<int DIN, int MIN, int MOUT, int OS>
__global__ __launch_bounds__(256) void ptl128_kernel(
    const float* __restrict__ x,
    const int* __restrict__ nidx,
    const unsigned* __restrict__ noff,
    const float* __restrict__ W,     // [4, DIN, 128]
    const float* __restrict__ Bb,    // [4, 128]
    const float* __restrict__ skipv, // [4] or null
    const float* __restrict__ hprev, // [N,128] or null
    float* __restrict__ out)
{
    constexpr int BK = 32;
    const int t = blockIdx.y;
    const unsigned s0 = noff[t], s1 = noff[t + 1];
    const unsigned base = s0 + blockIdx.x * 128u;
    if (base >= s1) return;
    const int nrows = (int)min(128u, s1 - base);

    __shared__ __align__(16) float xs[BK][128];
    __shared__ __align__(16) float wsl[BK][128];
    __shared__ int nid[128];

    const int tid = threadIdx.x;
    if (tid < 128) nid[tid] = nidx[base + (unsigned)min(tid, nrows - 1)];
    __syncthreads();

    const int tx = tid & 15;   // col group: cols tx*8 .. +8
    const int ty = tid >> 4;   // row group: rows ty*8 .. +8
    const int row = tid & 127, kg = tid >> 7;   // x staging: 16 k's per thread

    float acc[8][8];
    #pragma unroll
    for (int m = 0; m < 8; m++)
        #pragma unroll
        for (int j = 0; j < 8; j++) acc[m][j] = 0.0f;

    const float* Wt = W + (size_t)t * DIN * 128;

    for (int k0 = 0; k0 < DIN; k0 += BK) {
        {
            // x: 64B/lane granule, transpose into xs
            const float* xp = x + (size_t)nid[row] * DIN + k0 + kg * 16;
            float4 a0 = ((const float4*)xp)[0];
            float4 a1 = ((const float4*)xp)[1];
            float4 a2 = ((const float4*)xp)[2];
            float4 a3 = ((const float4*)xp)[3];
            float v[16] = {a0.x, a0.y, a0.z, a0.w, a1.x, a1.y, a1.z, a1.w,
                           a2.x, a2.y, a2.z, a2.w, a3.x, a3.y, a3.z, a3.w};
            #pragma unroll
            for (int i = 0; i < 16; i++) {
                float q = v[i];
                if (MIN == 1) q = gelu_f(q);
                xs[kg * 16 + i][row] = q;
            }
        }
        {
            // W: flat 64B/lane chunks, contiguous across the wave
            const float* wp = Wt + (size_t)k0 * 128 + tid * 16;
            #pragma unroll
            for (int i = 0; i < 4; i++)
                *(float4*)&wsl[0][tid * 16 + 4 * i] = ((const float4*)wp)[i];
        }
        __syncthreads();
        #pragma unroll 8
        for (int kk = 0; kk < BK; kk++) {
            float4 xa = *(float4*)&xs[kk][ty * 8];
            float4 xb = *(float4*)&xs[kk][ty * 8 + 4];
            float4 wa = *(float4*)&wsl[kk][tx * 8];
            float4 wb = *(float4*)&wsl[kk][tx * 8 + 4];
            float xv[8] = {xa.x, xa.y, xa.z, xa.w, xb.x, xb.y, xb.z, xb.w};
            float wv[8] = {wa.x, wa.y, wa.z, wa.w, wb.x, wb.y, wb.z, wb.w};
            #pragma unroll
            for (int m = 0; m < 8; m++)
                #pragma unroll
                for (int j = 0; j < 8; j++)
                    acc[m][j] += xv[m] * wv[j];
        }
        __syncthreads();
    }

    float alpha = 0.0f;
    if (MOUT == 2) alpha = sigmoid_f(skipv[t]);
    float bb[8];
    #pragma unroll
    for (int j = 0; j < 8; j++) bb[j] = Bb[t * 128 + tx * 8 + j];

    #pragma unroll
    for (int m = 0; m < 8; m++) {
        int rr = ty * 8 + m;
        if (rr < nrows) {
            int n = nid[rr];
            float o[8];
            #pragma unroll
            for (int j = 0; j < 8; j++) o[j] = acc[m][j] + bb[j];
            if (MOUT == 0) {
                #pragma unroll
                for (int j = 0; j < 8; j++) o[j] = tanhf(o[j]);
            } else if (MOUT == 2) {
                const float* hp = hprev + (size_t)n * 128 + tx * 8;
                float4 h0 = *(const float4*)(hp);
                float4 h1 = *(const float4*)(hp + 4);
                float hv[8] = {h0.x, h0.y, h0.z, h0.w, h1.x, h1.y, h1.z, h1.w};
                #pragma unroll
                for (int j = 0; j < 8; j++)
                    o[j] = o[j] * alpha + hv[j] * (1.0f - alpha);
            }
            if (OS == 1) {
                float* op = out + (size_t)n * 128 + tx * 8;
                *(float4*)(op)     = make_float4(o[0], o[1], o[2], o[3]);
                *(float4*)(op + 4) = make_float4(o[4], o[5], o[6], o[7]);
            } else {
                float* op = out + ((size_t)n * 128 + tx * 8) * OS;
                #pragma unroll
                for (int j = 0; j < 8; j++) op[j * OS] = o[j];
            }
        }
    }
}

// ---------------- fused edge phase: score + softmax + aggregate ----------------
// R10 structure; k/v INTERLEAVED in one buffer (kv[node][dim] = {k,v} pairs):
// one global_load_dwordx2 per edge per lane instead of two scattered dword
// gathers -> halves VMEM issue count (the MLP/issue limiter at 12.5% HBM).
__global__ __launch_bounds__(256) void hgt_edge_fused(
    const int* __restrict__ er_t,       // packed (src<<3)|rel, sorted by tgt
    const unsigned* __restrict__ eoff,  // [NN+1]
    const float* __restrict__ kv,       // [NN][128][2] interleaved k,v
    const float* __restrict__ att,      // [8,8,16,16] layer slice
    const float* __restrict__ msg,      // [8,8,16,16] layer slice
    const float* __restrict__ pri,      // [8,8]
    float* __restrict__ qagg)           // q in, agg out (in-place per target)
{
    __shared__ float aq_lds[2][1024];
    __shared__ float pv_lds[2][1024];
    const int tid  = threadIdx.x;
    const int tsel = tid >> 7;
    const int li   = tid & 127;
    const int h    = li >> 4;
    const int j    = li & 15;
    const int l    = tid & 63;
    const int hb   = tid & 0x30;
    const int t    = blockIdx.x * 2 + tsel;
    if (t >= NN) return;

    const unsigned e0 = eoff[t];
    const unsigned e1 = eoff[t + 1];
    const int deg = (int)(e1 - e0);

    if (deg == 0) {
        qagg[(size_t)t * 128 + li] = 0.0f;
        return;
    }

    float* al = aq_lds[tsel];
    float* pl = pv_lds[tsel];

    #pragma unroll
    for (int r = 0; r < 8; r++) pl[r * 128 + li] = 0.0f;

    const float qo = qagg[(size_t)t * 128 + li];
    float qh[16];
    #pragma unroll
    for (int f = 0; f < 16; f++) qh[f] = __shfl(qo, hb + f, 64);

    int pkl = 0;
    if (l < 16 && e0 + (unsigned)l < e1) pkl = er_t[e0 + l];

    const int dc = min(deg, 16);
    unsigned mask = 0;
    for (int c = 0; c < dc; ++c) mask |= 1u << (__shfl(pkl, c, 64) & 7);
    for (unsigned e = e0 + 16; e < e1; ++e) mask |= 1u << (er_t[e] & 7);

    unsigned need = mask;
    while (need) {
        const int r = __ffs(need) - 1; need &= need - 1;
        const float* Ar = att + (((r * 8 + h) * 16 + j) * 16);
        float4 A0 = ((const float4*)Ar)[0];
        float4 A1 = ((const float4*)Ar)[1];
        float4 A2 = ((const float4*)Ar)[2];
        float4 A3 = ((const float4*)Ar)[3];
        float acc =
            A0.x*qh[0]  + A0.y*qh[1]  + A0.z*qh[2]  + A0.w*qh[3]  +
            A1.x*qh[4]  + A1.y*qh[5]  + A1.z*qh[6]  + A1.w*qh[7]  +
            A2.x*qh[8]  + A2.y*qh[9]  + A2.z*qh[10] + A2.w*qh[11] +
            A3.x*qh[12] + A3.y*qh[13] + A3.z*qh[14] + A3.w*qh[15];
        al[r * 128 + li] = acc * pri[r * 8 + h] * 0.25f;
    }

    float z = 0.0f;
    float* plp = pl + li;
    const float* alp = al + li;
    const float* kvb = kv + li * 2;     // lane-folded base into interleaved pairs

    unsigned e = e0;
    // main: 4 edges per step, 4 dwordx2 gathers in flight, no per-element guards
    for (; e + 4 <= e1; e += 4) {
        const int o = (int)(e - e0);
        int p0, p1, p2, p3;
        if (o + 3 < 16) {
            p0 = __shfl(pkl, o + 0, 64);
            p1 = __shfl(pkl, o + 1, 64);
            p2 = __shfl(pkl, o + 2, 64);
            p3 = __shfl(pkl, o + 3, 64);
        } else {
            p0 = er_t[e + 0]; p1 = er_t[e + 1];
            p2 = er_t[e + 2]; p3 = er_t[e + 3];
        }
        const int o0 = (p0 & ~7) << 5;   // src*256 (pair-elements), no mul
        const int o1 = (p1 & ~7) << 5;
        const int o2 = (p2 & ~7) << 5;
        const int o3 = (p3 & ~7) << 5;
        const float2 kv0 = *(const float2*)&kvb[o0];
        const float2 kv1 = *(const float2*)&kvb[o1];
        const float2 kv2 = *(const float2*)&kvb[o2];
        const float2 kv3 = *(const float2*)&kvb[o3];
        float s0 = kv0.x * alp[(p0 & 7) * 128];
        float s1 = kv1.x * alp[(p1 & 7) * 128];
        float s2 = kv2.x * alp[(p2 & 7) * 128];
        float s3 = kv3.x * alp[(p3 & 7) * 128];
        s0 += __shfl_xor(s0, 1); s1 += __shfl_xor(s1, 1);
        s2 += __shfl_xor(s2, 1); s3 += __shfl_xor(s3, 1);
        s0 += __shfl_xor(s0, 2); s1 += __shfl_xor(s1, 2);
        s2 += __shfl_xor(s2, 2); s3 += __shfl_xor(s3, 2);
        s0 += __shfl_xor(s0, 4); s1 += __shfl_xor(s1, 4);
        s2 += __shfl_xor(s2, 4); s3 += __shfl_xor(s3, 4);
        s0 += __shfl_xor(s0, 8); s1 += __shfl_xor(s1, 8);
        s2 += __shfl_xor(s2, 8); s3 += __shfl_xor(s3, 8);
        const float q0 = __expf(s0 - 8.0f);
        const float q1 = __expf(s1 - 8.0f);
        const float q2 = __expf(s2 - 8.0f);
        const float q3 = __expf(s3 - 8.0f);
        z += q0 + q1 + q2 + q3;
        plp[(p0 & 7) * 128] += q0 * kv0.y;   // same-thread RMWs serialize correctly
        plp[(p1 & 7) * 128] += q1 * kv1.y;
        plp[(p2 & 7) * 128] += q2 * kv2.y;
        plp[(p3 & 7) * 128] += q3 * kv3.y;
    }
    // tail: one 2-wide step, then one 1-wide step (uniform branches)
    if (e + 2 <= e1) {
        const int o = (int)(e - e0);
        int p0, p1;
        if (o + 1 < 16) { p0 = __shfl(pkl, o, 64); p1 = __shfl(pkl, o + 1, 64); }
        else            { p0 = er_t[e]; p1 = er_t[e + 1]; }
        const int o0 = (p0 & ~7) << 5;
        const int o1 = (p1 & ~7) << 5;
        const float2 kv0 = *(const float2*)&kvb[o0];
        const float2 kv1 = *(const float2*)&kvb[o1];
        float s0 = kv0.x * alp[(p0 & 7) * 128];
        float s1 = kv1.x * alp[(p1 & 7) * 128];
        s0 += __shfl_xor(s0, 1); s1 += __shfl_xor(s1, 1);
        s0 += __shfl_xor(s0, 2); s1 += __shfl_xor(s1, 2);
        s0 += __shfl_xor(s0, 4); s1 += __shfl_xor(s1, 4);
        s0 += __shfl_xor(s0, 8); s1 += __shfl_xor(s1, 8);
        const float q0 = __expf(s0 - 8.0f);
        const float q1 = __expf(s1 - 8.0f);
        z += q0 + q1;
        plp[(p0 & 7) * 128] += q0 * kv0.y;
        plp[(p1 & 7) * 128] += q1 * kv1.y;
        e += 2;
    }
    if (e < e1) {
        const int o = (int)(e - e0);
        const int p0 = (o < 16) ? __shfl(pkl, o, 64) : er_t[e];
        const int o0 = (p0 & ~7) << 5;
        const float2 kv0 = *(const float2*)&kvb[o0];
        float s0 = kv0.x * alp[(p0 & 7) * 128];
        s0 += __shfl_xor(s0, 1);
        s0 += __shfl_xor(s0, 2);
        s0 += __shfl_xor(s0, 4);
        s0 += __shfl_xor(s0, 8);
        const float q0 = __expf(s0 - 8.0f);
        z += q0;
        plp[(p0 & 7) * 128] += q0 * kv0.y;
    }

    // epilogue (R8/R10 form): sb[d] = LDS same-address broadcast within each
    // 16-lane group; Mr[d*16] = 64B-coalesced VMEM across the j-lanes.
    float acc = 0.0f;
    for (int r = 0; r < 8; r++) {
        if (!((mask >> r) & 1)) continue;
        const float* Mr = msg + ((r * 8 + h) * 256) + j;
        const float* sb = pl + r * 128 + h * 16;
        #pragma unroll
        for (int d = 0; d < 16; d++)
            acc += sb[d] * Mr[d * 16];
    }
    qagg[(size_t)t * 128 + li] = acc * __frcp_rn(z + 1e-9f);
}

// ---------------- launch ----------------
extern "C" void kernel_launch(void* const* d_in, const int* in_sizes, int n_in,
                              void* d_out, int out_size, void* d_ws, size_t ws_size,
                              hipStream_t stream)
{
    const float* node_feature = (const float*)d_in[0];
    const int*   node_type    = (const int*)d_in[1];
    const int*   edge_index   = (const int*)d_in[2];
    const int*   edge_type    = (const int*)d_in[3];
    const float* adapt_w      = (const float*)d_in[4];
    const float* adapt_b      = (const float*)d_in[5];
    const float* k_w = (const float*)d_in[6];
    const float* k_b = (const float*)d_in[7];
    const float* q_w = (const float*)d_in[8];
    const float* q_b = (const float*)d_in[9];
    const float* v_w = (const float*)d_in[10];
    const float* v_b = (const float*)d_in[11];
    const float* a_w = (const float*)d_in[12];
    const float* a_b = (const float*)d_in[13];
    const float* rel_pri = (const float*)d_in[14];
    const float* rel_att = (const float*)d_in[15];
    const float* rel_msg = (const float*)d_in[16];
    const float* skip    = (const float*)d_in[17];

    const int* src = edge_index;
    const int* tgt = edge_index + NE;

    float* OUT = (float*)d_out;

    char* w = (char*)d_ws;
    auto alloc = [&](size_t bytes) -> void* {
        void* p = (void*)w;
        w += (bytes + 255) & ~(size_t)255;
        return p;
    };
    float*    B0    = (float*)alloc((size_t)NN * 128 * 4);
    float*    B1    = (float*)alloc((size_t)NN * 128 * 4);
    float*    KV    = (float*)alloc((size_t)NN * 256 * 4);   // interleaved k,v
    int*      nidx  = (int*)alloc((size_t)NN * 4);
    int*      er_t  = (int*)alloc((size_t)NE * 4);
    unsigned* tcnt  = (unsigned*)alloc((size_t)NN * 4);
    unsigned* eoff  = (unsigned*)alloc((size_t)(NN + 1) * 4);
    unsigned* ecur  = (unsigned*)alloc((size_t)NN * 4);
    unsigned* bsum  = (unsigned*)alloc((size_t)NBLK * 4);
    unsigned* cnts  = (unsigned*)alloc(16 * 4);

    unsigned* ncnt = cnts;          // 4
    unsigned* ncur = cnts + 4;      // 4
    unsigned* noff = cnts + 8;      // 5

    hipMemsetAsync(cnts, 0, 16 * 4, stream);
    hipMemsetAsync(tcnt, 0, (size_t)NN * 4, stream);

    const int gblocks = (NE + 255) / 256;
    count2_kernel<<<gblocks, 256, 0, stream>>>(node_type, tgt, ncnt, tcnt);
    node_offsets_kernel<<<1, 1, 0, stream>>>(cnts);
    scan1_kernel<<<NBLK, 256, 0, stream>>>(tcnt, eoff, bsum);
    scan2_kernel<<<1, 512, 0, stream>>>(bsum);
    scan3_kernel<<<NBLK, 256, 0, stream>>>(eoff, bsum, ecur);
    scatter2_kernel<<<gblocks, 256, 0, stream>>>(node_type, src, tgt, edge_type,
                                                 ncur, ecur, nidx, er_t);

    dim3 pgrid((NN + 127) / 128, N_TYPES);
    ptl128_kernel<IN_DIM, 0, 0, 1><<<pgrid, 256, 0, stream>>>(
        node_feature, nidx, noff, adapt_w, adapt_b, nullptr, nullptr, B0);

    const int fblocks = (NN + 1) / 2;

    for (int l = 0; l < N_LAYERS; l++) {
        // buffers: hin -> {k,v interleaved in KV; q} -> edge(agg in q) -> out
        float* hin  = l ? B1 : B0;
        float* qb_  = l ? B0 : OUT;   // q, then agg in-place
        float* hout = l ? OUT : B1;

        const float* kwl = k_w + (size_t)l * N_TYPES * 128 * 128;
        const float* kbl = k_b + (size_t)l * N_TYPES * 128;
        const float* qwl = q_w + (size_t)l * N_TYPES * 128 * 128;
        const float* qbl = q_b + (size_t)l * N_TYPES * 128;
        const float* vwl = v_w + (size_t)l * N_TYPES * 128 * 128;
        const float* vbl = v_b + (size_t)l * N_TYPES * 128;
        const float* awl = a_w + (size_t)l * N_TYPES * 128 * 128;
        const float* abl = a_b + (size_t)l * N_TYPES * 128;
        const float* pril = rel_pri + (size_t)l * N_REL * N_HEADS;
        const float* attl = rel_att + (size_t)l * N_REL * N_HEADS * D_K * D_K;
        const float* msgl = rel_msg + (size_t)l * N_REL * N_HEADS * D_K * D_K;
        const float* skipl = skip + (size_t)l * N_TYPES;

        ptl128_kernel<N_HID, 0, 1, 2><<<pgrid, 256, 0, stream>>>(
            hin, nidx, noff, kwl, kbl, nullptr, nullptr, KV);       // k -> even
        ptl128_kernel<N_HID, 0, 1, 1><<<pgrid, 256, 0, stream>>>(
            hin, nidx, noff, qwl, qbl, nullptr, nullptr, qb_);
        ptl128_kernel<N_HID, 0, 1, 2><<<pgrid, 256, 0, stream>>>(
            hin, nidx, noff, vwl, vbl, nullptr, nullptr, KV + 1);   // v -> odd

        hgt_edge_fused<<<fblocks, 256, 0, stream>>>(
            er_t, eoff, KV, attl, msgl, pril, qb_);

        ptl128_kernel<N_HID, 1, 2, 1><<<pgrid, 256, 0, stream>>>(
            qb_, nidx, noff, awl, abl, skipl, hin, hout);
    }
}

// Round 13
// 1197.766 us; speedup vs baseline: 1.1939x; 1.1939x over previous
//
#include <hip/hip_runtime.h>
#include <hip/hip_fp16.h>
#include <math.h>

constexpr int N_TYPES = 4;
constexpr int N_REL   = 8;
constexpr int N_HEADS = 8;
constexpr int IN_DIM  = 256;
constexpr int N_HID   = 128;
constexpr int D_K     = 16;
constexpr int N_LAYERS= 2;
constexpr int NN      = 100000;
constexpr int NE      = 400000;
constexpr int NBLK    = (NN + 255) / 256;   // scan blocks

__device__ __forceinline__ float gelu_f(float x) {
    const float c = 0.7978845608028654f; // sqrt(2/pi)
    float x3 = x * x * x;
    return 0.5f * x * (1.0f + tanhf(c * (x + 0.044715f * x3)));
}
__device__ __forceinline__ float sigmoid_f(float x) {
    return 1.0f / (1.0f + expf(-x));
}

// ---------------- bucketing: nodes by type, edges by target ----------------
__global__ __launch_bounds__(256) void count2_kernel(
    const int* __restrict__ ntype, const int* __restrict__ tgt,
    unsigned* ncnt, unsigned* tcnt)
{
    int i = blockIdx.x * 256 + threadIdx.x;
    int lane = threadIdx.x & 63;
    int t = (i < NN) ? ntype[i] : -1;
    #pragma unroll
    for (int tt = 0; tt < N_TYPES; tt++) {
        unsigned long long m = __ballot(t == tt);
        if (m != 0ull && lane == __ffsll((unsigned long long)m) - 1)
            atomicAdd(&ncnt[tt], (unsigned)__popcll(m));
    }
    if (i < NE) atomicAdd(&tcnt[tgt[i]], 1u);
}

__global__ void node_offsets_kernel(unsigned* c)
{
    // layout: ncnt[0:4] ncur[4:8] noff[8:13]
    unsigned a = 0;
    for (int t = 0; t < N_TYPES; t++) { c[8 + t] = a; c[4 + t] = a; a += c[t]; }
    c[8 + N_TYPES] = a;
}

// hierarchical exclusive scan over tcnt[NN] -> eoff[NN+1]
__global__ __launch_bounds__(256) void scan1_kernel(
    const unsigned* __restrict__ cnt, unsigned* __restrict__ eoff,
    unsigned* __restrict__ bsum)
{
    __shared__ unsigned sh[256];
    int i = blockIdx.x * 256 + threadIdx.x;
    unsigned v = (i < NN) ? cnt[i] : 0u;
    sh[threadIdx.x] = v;
    __syncthreads();
    for (int off = 1; off < 256; off <<= 1) {
        unsigned add = (threadIdx.x >= off) ? sh[threadIdx.x - off] : 0u;
        __syncthreads();
        sh[threadIdx.x] += add;
        __syncthreads();
    }
    if (i < NN) eoff[i] = sh[threadIdx.x] - v;      // block-local exclusive
    if (threadIdx.x == 255) bsum[blockIdx.x] = sh[255];
}

__global__ __launch_bounds__(512) void scan2_kernel(unsigned* __restrict__ bsum)
{
    __shared__ unsigned sh[512];
    int i = threadIdx.x;
    unsigned v = (i < NBLK) ? bsum[i] : 0u;
    sh[i] = v;
    __syncthreads();
    for (int off = 1; off < 512; off <<= 1) {
        unsigned add = (i >= off) ? sh[i - off] : 0u;
        __syncthreads();
        sh[i] += add;
        __syncthreads();
    }
    if (i < NBLK) bsum[i] = sh[i] - v;              // exclusive block offsets
}

__global__ __launch_bounds__(256) void scan3_kernel(
    unsigned* __restrict__ eoff, const unsigned* __restrict__ bsum,
    unsigned* __restrict__ ecur)
{
    int i = blockIdx.x * 256 + threadIdx.x;
    if (i < NN) {
        unsigned v = eoff[i] + bsum[blockIdx.x];
        eoff[i] = v;
        ecur[i] = v;
    }
    if (i == 0) eoff[NN] = (unsigned)NE;
}

__global__ __launch_bounds__(256) void scatter2_kernel(
    const int* __restrict__ ntype,
    const int* __restrict__ src, const int* __restrict__ tgt,
    const int* __restrict__ etype,
    unsigned* ncur, unsigned* ecur,
    int* __restrict__ nidx,
    int* __restrict__ er_t)            // packed (src<<3) | rel
{
    int i = blockIdx.x * 256 + threadIdx.x;
    int lane = threadIdx.x & 63;
    int t = (i < NN) ? ntype[i] : -1;
    // wave-aggregated slot assignment: 1 atomic per (wave, type) not per node
    #pragma unroll
    for (int tt = 0; tt < N_TYPES; tt++) {
        unsigned long long m = __ballot(t == tt);
        if (m == 0ull) continue;
        int leader = __ffsll((unsigned long long)m) - 1;
        unsigned base = 0;
        if (lane == leader) base = atomicAdd(&ncur[tt], (unsigned)__popcll(m));
        base = __shfl(base, leader, 64);
        if (t == tt) {
            unsigned rank = (unsigned)__popcll(m & ((1ull << lane) - 1ull));
            nidx[base + rank] = i;
        }
    }
    if (i < NE) {
        int tg = tgt[i];
        unsigned p = atomicAdd(&ecur[tg], 1u);   // 100K distinct addrs, low contention
        er_t[p] = (src[i] << 3) | etype[i];
    }
}

// ---------------- per-type linear, 128x128 tile, 8x8 per thread, BK=32 ------
// MIN: 0 = plain input, 1 = gelu(input)
// MOUT: 0 = tanh(out), 1 = plain (+bias), 2 = skip-mix with hprev
// OH: 0 = fp32 output, 1 = fp16 output (coalesced 16B stores)
template<int DIN, int MIN, int MOUT, int OH>
__global__ __launch_bounds__(256) void ptl128_kernel(
    const float* __restrict__ x,
    const int* __restrict__ nidx,
    const unsigned* __restrict__ noff,
    const float* __restrict__ W,     // [4, DIN, 128]
    const float* __restrict__ Bb,    // [4, 128]
    const float* __restrict__ skipv, // [4] or null
    const float* __restrict__ hprev, // [N,128] or null
    void* __restrict__ out)
{
    constexpr int BK = 32;
    const int t = blockIdx.y;
    const unsigned s0 = noff[t], s1 = noff[t + 1];
    const unsigned base = s0 + blockIdx.x * 128u;
    if (base >= s1) return;
    const int nrows = (int)min(128u, s1 - base);

    __shared__ __align__(16) float xs[BK][128];
    __shared__ __align__(16) float wsl[BK][128];
    __shared__ int nid[128];

    const int tid = threadIdx.x;
    if (tid < 128) nid[tid] = nidx[base + (unsigned)min(tid, nrows - 1)];
    __syncthreads();

    const int tx = tid & 15;   // col group: cols tx*8 .. +8
    const int ty = tid >> 4;   // row group: rows ty*8 .. +8
    const int row = tid & 127, kg = tid >> 7;   // x staging: 16 k's per thread

    float acc[8][8];
    #pragma unroll
    for (int m = 0; m < 8; m++)
        #pragma unroll
        for (int j = 0; j < 8; j++) acc[m][j] = 0.0f;

    const float* Wt = W + (size_t)t * DIN * 128;

    for (int k0 = 0; k0 < DIN; k0 += BK) {
        {
            // x: 64B/lane granule, transpose into xs
            const float* xp = x + (size_t)nid[row] * DIN + k0 + kg * 16;
            float4 a0 = ((const float4*)xp)[0];
            float4 a1 = ((const float4*)xp)[1];
            float4 a2 = ((const float4*)xp)[2];
            float4 a3 = ((const float4*)xp)[3];
            float v[16] = {a0.x, a0.y, a0.z, a0.w, a1.x, a1.y, a1.z, a1.w,
                           a2.x, a2.y, a2.z, a2.w, a3.x, a3.y, a3.z, a3.w};
            #pragma unroll
            for (int i = 0; i < 16; i++) {
                float q = v[i];
                if (MIN == 1) q = gelu_f(q);
                xs[kg * 16 + i][row] = q;
            }
        }
        {
            // W: flat 64B/lane chunks, contiguous across the wave
            const float* wp = Wt + (size_t)k0 * 128 + tid * 16;
            #pragma unroll
            for (int i = 0; i < 4; i++)
                *(float4*)&wsl[0][tid * 16 + 4 * i] = ((const float4*)wp)[i];
        }
        __syncthreads();
        #pragma unroll 8
        for (int kk = 0; kk < BK; kk++) {
            float4 xa = *(float4*)&xs[kk][ty * 8];
            float4 xb = *(float4*)&xs[kk][ty * 8 + 4];
            float4 wa = *(float4*)&wsl[kk][tx * 8];
            float4 wb = *(float4*)&wsl[kk][tx * 8 + 4];
            float xv[8] = {xa.x, xa.y, xa.z, xa.w, xb.x, xb.y, xb.z, xb.w};
            float wv[8] = {wa.x, wa.y, wa.z, wa.w, wb.x, wb.y, wb.z, wb.w};
            #pragma unroll
            for (int m = 0; m < 8; m++)
                #pragma unroll
                for (int j = 0; j < 8; j++)
                    acc[m][j] += xv[m] * wv[j];
        }
        __syncthreads();
    }

    float alpha = 0.0f;
    if (MOUT == 2) alpha = sigmoid_f(skipv[t]);
    float bb[8];
    #pragma unroll
    for (int j = 0; j < 8; j++) bb[j] = Bb[t * 128 + tx * 8 + j];

    #pragma unroll
    for (int m = 0; m < 8; m++) {
        int rr = ty * 8 + m;
        if (rr < nrows) {
            int n = nid[rr];
            float o[8];
            #pragma unroll
            for (int j = 0; j < 8; j++) o[j] = acc[m][j] + bb[j];
            if (MOUT == 0) {
                #pragma unroll
                for (int j = 0; j < 8; j++) o[j] = tanhf(o[j]);
            } else if (MOUT == 2) {
                const float* hp = hprev + (size_t)n * 128 + tx * 8;
                float4 h0 = *(const float4*)(hp);
                float4 h1 = *(const float4*)(hp + 4);
                float hv[8] = {h0.x, h0.y, h0.z, h0.w, h1.x, h1.y, h1.z, h1.w};
                #pragma unroll
                for (int j = 0; j < 8; j++)
                    o[j] = o[j] * alpha + hv[j] * (1.0f - alpha);
            }
            if (OH == 0) {
                float* op = (float*)out + (size_t)n * 128 + tx * 8;
                *(float4*)(op)     = make_float4(o[0], o[1], o[2], o[3]);
                *(float4*)(op + 4) = make_float4(o[4], o[5], o[6], o[7]);
            } else {
                __align__(16) __half hh[8];
                #pragma unroll
                for (int j = 0; j < 8; j++) hh[j] = __float2half(o[j]);
                __half* op = (__half*)out + (size_t)n * 128 + tx * 8;
                *(uint4*)op = *(uint4*)hh;   // 16B coalesced
            }
        }
    }
}

// ---------------- fused edge phase: score + softmax + aggregate ----------------
// R10 structure; k/v gathered as fp16 (half the random-gather bytes — the
// measured limiter: dur tracks FETCH/1TB/s across all instruction variants).
// q, accumulators, att/msg stay fp32.
__global__ __launch_bounds__(256) void hgt_edge_fused(
    const int* __restrict__ er_t,       // packed (src<<3)|rel, sorted by tgt
    const unsigned* __restrict__ eoff,  // [NN+1]
    const __half* __restrict__ kh,      // [NN][128] fp16
    const __half* __restrict__ vh,      // [NN][128] fp16
    const float* __restrict__ att,      // [8,8,16,16] layer slice
    const float* __restrict__ msg,      // [8,8,16,16] layer slice
    const float* __restrict__ pri,      // [8,8]
    float* __restrict__ qagg)           // q in, agg out (in-place per target)
{
    __shared__ float aq_lds[2][1024];
    __shared__ float pv_lds[2][1024];
    const int tid  = threadIdx.x;
    const int tsel = tid >> 7;
    const int li   = tid & 127;
    const int h    = li >> 4;
    const int j    = li & 15;
    const int l    = tid & 63;
    const int hb   = tid & 0x30;
    const int t    = blockIdx.x * 2 + tsel;
    if (t >= NN) return;

    const unsigned e0 = eoff[t];
    const unsigned e1 = eoff[t + 1];
    const int deg = (int)(e1 - e0);

    if (deg == 0) {
        qagg[(size_t)t * 128 + li] = 0.0f;
        return;
    }

    float* al = aq_lds[tsel];
    float* pl = pv_lds[tsel];

    #pragma unroll
    for (int r = 0; r < 8; r++) pl[r * 128 + li] = 0.0f;

    const float qo = qagg[(size_t)t * 128 + li];
    float qh[16];
    #pragma unroll
    for (int f = 0; f < 16; f++) qh[f] = __shfl(qo, hb + f, 64);

    int pkl = 0;
    if (l < 16 && e0 + (unsigned)l < e1) pkl = er_t[e0 + l];

    const int dc = min(deg, 16);
    unsigned mask = 0;
    for (int c = 0; c < dc; ++c) mask |= 1u << (__shfl(pkl, c, 64) & 7);
    for (unsigned e = e0 + 16; e < e1; ++e) mask |= 1u << (er_t[e] & 7);

    unsigned need = mask;
    while (need) {
        const int r = __ffs(need) - 1; need &= need - 1;
        const float* Ar = att + (((r * 8 + h) * 16 + j) * 16);
        float4 A0 = ((const float4*)Ar)[0];
        float4 A1 = ((const float4*)Ar)[1];
        float4 A2 = ((const float4*)Ar)[2];
        float4 A3 = ((const float4*)Ar)[3];
        float acc =
            A0.x*qh[0]  + A0.y*qh[1]  + A0.z*qh[2]  + A0.w*qh[3]  +
            A1.x*qh[4]  + A1.y*qh[5]  + A1.z*qh[6]  + A1.w*qh[7]  +
            A2.x*qh[8]  + A2.y*qh[9]  + A2.z*qh[10] + A2.w*qh[11] +
            A3.x*qh[12] + A3.y*qh[13] + A3.z*qh[14] + A3.w*qh[15];
        al[r * 128 + li] = acc * pri[r * 8 + h] * 0.25f;
    }

    float z = 0.0f;
    float* plp = pl + li;
    const float* alp = al + li;
    const __half* kb = kh + li;         // lane-folded bases
    const __half* vb = vh + li;

    unsigned e = e0;
    // main: 4 edges per step, 8 ushort gathers in flight, no per-element guards
    for (; e + 4 <= e1; e += 4) {
        const int o = (int)(e - e0);
        int p0, p1, p2, p3;
        if (o + 3 < 16) {
            p0 = __shfl(pkl, o + 0, 64);
            p1 = __shfl(pkl, o + 1, 64);
            p2 = __shfl(pkl, o + 2, 64);
            p3 = __shfl(pkl, o + 3, 64);
        } else {
            p0 = er_t[e + 0]; p1 = er_t[e + 1];
            p2 = er_t[e + 2]; p3 = er_t[e + 3];
        }
        const int o0 = (p0 & ~7) << 4;   // src*128, no mul
        const int o1 = (p1 & ~7) << 4;
        const int o2 = (p2 & ~7) << 4;
        const int o3 = (p3 & ~7) << 4;
        const float k0 = __half2float(kb[o0]); const float v0 = __half2float(vb[o0]);
        const float k1 = __half2float(kb[o1]); const float v1 = __half2float(vb[o1]);
        const float k2 = __half2float(kb[o2]); const float v2 = __half2float(vb[o2]);
        const float k3 = __half2float(kb[o3]); const float v3 = __half2float(vb[o3]);
        float s0 = k0 * alp[(p0 & 7) * 128];
        float s1 = k1 * alp[(p1 & 7) * 128];
        float s2 = k2 * alp[(p2 & 7) * 128];
        float s3 = k3 * alp[(p3 & 7) * 128];
        s0 += __shfl_xor(s0, 1); s1 += __shfl_xor(s1, 1);
        s2 += __shfl_xor(s2, 1); s3 += __shfl_xor(s3, 1);
        s0 += __shfl_xor(s0, 2); s1 += __shfl_xor(s1, 2);
        s2 += __shfl_xor(s2, 2); s3 += __shfl_xor(s3, 2);
        s0 += __shfl_xor(s0, 4); s1 += __shfl_xor(s1, 4);
        s2 += __shfl_xor(s2, 4); s3 += __shfl_xor(s3, 4);
        s0 += __shfl_xor(s0, 8); s1 += __shfl_xor(s1, 8);
        s2 += __shfl_xor(s2, 8); s3 += __shfl_xor(s3, 8);
        const float q0 = __expf(s0 - 8.0f);
        const float q1 = __expf(s1 - 8.0f);
        const float q2 = __expf(s2 - 8.0f);
        const float q3 = __expf(s3 - 8.0f);
        z += q0 + q1 + q2 + q3;
        plp[(p0 & 7) * 128] += q0 * v0;   // same-thread RMWs serialize correctly
        plp[(p1 & 7) * 128] += q1 * v1;
        plp[(p2 & 7) * 128] += q2 * v2;
        plp[(p3 & 7) * 128] += q3 * v3;
    }
    // tail: one 2-wide step, then one 1-wide step (uniform branches)
    if (e + 2 <= e1) {
        const int o = (int)(e - e0);
        int p0, p1;
        if (o + 1 < 16) { p0 = __shfl(pkl, o, 64); p1 = __shfl(pkl, o + 1, 64); }
        else            { p0 = er_t[e]; p1 = er_t[e + 1]; }
        const int o0 = (p0 & ~7) << 4;
        const int o1 = (p1 & ~7) << 4;
        const float k0 = __half2float(kb[o0]); const float v0 = __half2float(vb[o0]);
        const float k1 = __half2float(kb[o1]); const float v1 = __half2float(vb[o1]);
        float s0 = k0 * alp[(p0 & 7) * 128];
        float s1 = k1 * alp[(p1 & 7) * 128];
        s0 += __shfl_xor(s0, 1); s1 += __shfl_xor(s1, 1);
        s0 += __shfl_xor(s0, 2); s1 += __shfl_xor(s1, 2);
        s0 += __shfl_xor(s0, 4); s1 += __shfl_xor(s1, 4);
        s0 += __shfl_xor(s0, 8); s1 += __shfl_xor(s1, 8);
        const float q0 = __expf(s0 - 8.0f);
        const float q1 = __expf(s1 - 8.0f);
        z += q0 + q1;
        plp[(p0 & 7) * 128] += q0 * v0;
        plp[(p1 & 7) * 128] += q1 * v1;
        e += 2;
    }
    if (e < e1) {
        const int o = (int)(e - e0);
        const int p0 = (o < 16) ? __shfl(pkl, o, 64) : er_t[e];
        const int o0 = (p0 & ~7) << 4;
        const float k0 = __half2float(kb[o0]); const float v0 = __half2float(vb[o0]);
        float s0 = k0 * alp[(p0 & 7) * 128];
        s0 += __shfl_xor(s0, 1);
        s0 += __shfl_xor(s0, 2);
        s0 += __shfl_xor(s0, 4);
        s0 += __shfl_xor(s0, 8);
        const float q0 = __expf(s0 - 8.0f);
        z += q0;
        plp[(p0 & 7) * 128] += q0 * v0;
    }

    // epilogue (R8/R10 form): sb[d] = LDS same-address broadcast within each
    // 16-lane group; Mr[d*16] = 64B-coalesced VMEM across the j-lanes.
    float acc = 0.0f;
    for (int r = 0; r < 8; r++) {
        if (!((mask >> r) & 1)) continue;
        const float* Mr = msg + ((r * 8 + h) * 256) + j;
        const float* sb = pl + r * 128 + h * 16;
        #pragma unroll
        for (int d = 0; d < 16; d++)
            acc += sb[d] * Mr[d * 16];
    }
    qagg[(size_t)t * 128 + li] = acc * __frcp_rn(z + 1e-9f);
}

// ---------------- launch ----------------
extern "C" void kernel_launch(void* const* d_in, const int* in_sizes, int n_in,
                              void* d_out, int out_size, void* d_ws, size_t ws_size,
                              hipStream_t stream)
{
    const float* node_feature = (const float*)d_in[0];
    const int*   node_type    = (const int*)d_in[1];
    const int*   edge_index   = (const int*)d_in[2];
    const int*   edge_type    = (const int*)d_in[3];
    const float* adapt_w      = (const float*)d_in[4];
    const float* adapt_b      = (const float*)d_in[5];
    const float* k_w = (const float*)d_in[6];
    const float* k_b = (const float*)d_in[7];
    const float* q_w = (const float*)d_in[8];
    const float* q_b = (const float*)d_in[9];
    const float* v_w = (const float*)d_in[10];
    const float* v_b = (const float*)d_in[11];
    const float* a_w = (const float*)d_in[12];
    const float* a_b = (const float*)d_in[13];
    const float* rel_pri = (const float*)d_in[14];
    const float* rel_att = (const float*)d_in[15];
    const float* rel_msg = (const float*)d_in[16];
    const float* skip    = (const float*)d_in[17];

    const int* src = edge_index;
    const int* tgt = edge_index + NE;

    float* OUT = (float*)d_out;

    char* w = (char*)d_ws;
    auto alloc = [&](size_t bytes) -> void* {
        void* p = (void*)w;
        w += (bytes + 255) & ~(size_t)255;
        return p;
    };
    float*    B0    = (float*)alloc((size_t)NN * 128 * 4);
    float*    B1    = (float*)alloc((size_t)NN * 128 * 4);
    float*    B2    = (float*)alloc((size_t)NN * 128 * 4);
    __half*   KH    = (__half*)alloc((size_t)NN * 128 * 2);
    __half*   VH    = (__half*)alloc((size_t)NN * 128 * 2);
    int*      nidx  = (int*)alloc((size_t)NN * 4);
    int*      er_t  = (int*)alloc((size_t)NE * 4);
    unsigned* tcnt  = (unsigned*)alloc((size_t)NN * 4);
    unsigned* eoff  = (unsigned*)alloc((size_t)(NN + 1) * 4);
    unsigned* ecur  = (unsigned*)alloc((size_t)NN * 4);
    unsigned* bsum  = (unsigned*)alloc((size_t)NBLK * 4);
    unsigned* cnts  = (unsigned*)alloc(16 * 4);

    unsigned* ncnt = cnts;          // 4
    unsigned* ncur = cnts + 4;      // 4
    unsigned* noff = cnts + 8;      // 5

    hipMemsetAsync(cnts, 0, 16 * 4, stream);
    hipMemsetAsync(tcnt, 0, (size_t)NN * 4, stream);

    const int gblocks = (NE + 255) / 256;
    count2_kernel<<<gblocks, 256, 0, stream>>>(node_type, tgt, ncnt, tcnt);
    node_offsets_kernel<<<1, 1, 0, stream>>>(cnts);
    scan1_kernel<<<NBLK, 256, 0, stream>>>(tcnt, eoff, bsum);
    scan2_kernel<<<1, 512, 0, stream>>>(bsum);
    scan3_kernel<<<NBLK, 256, 0, stream>>>(eoff, bsum, ecur);
    scatter2_kernel<<<gblocks, 256, 0, stream>>>(node_type, src, tgt, edge_type,
                                                 ncur, ecur, nidx, er_t);

    dim3 pgrid((NN + 127) / 128, N_TYPES);
    ptl128_kernel<IN_DIM, 0, 0, 0><<<pgrid, 256, 0, stream>>>(
        node_feature, nidx, noff, adapt_w, adapt_b, nullptr, nullptr, B0);

    const int fblocks = (NN + 1) / 2;

    for (int l = 0; l < N_LAYERS; l++) {
        // buffers: hin -> {k,v fp16; q fp32 in B2} -> edge(agg in q) -> out
        float* hin  = l ? B1 : B0;
        float* qb_  = B2;            // q, then agg in-place
        float* hout = l ? OUT : B1;

        const float* kwl = k_w + (size_t)l * N_TYPES * 128 * 128;
        const float* kbl = k_b + (size_t)l * N_TYPES * 128;
        const float* qwl = q_w + (size_t)l * N_TYPES * 128 * 128;
        const float* qbl = q_b + (size_t)l * N_TYPES * 128;
        const float* vwl = v_w + (size_t)l * N_TYPES * 128 * 128;
        const float* vbl = v_b + (size_t)l * N_TYPES * 128;
        const float* awl = a_w + (size_t)l * N_TYPES * 128 * 128;
        const float* abl = a_b + (size_t)l * N_TYPES * 128;
        const float* pril = rel_pri + (size_t)l * N_REL * N_HEADS;
        const float* attl = rel_att + (size_t)l * N_REL * N_HEADS * D_K * D_K;
        const float* msgl = rel_msg + (size_t)l * N_REL * N_HEADS * D_K * D_K;
        const float* skipl = skip + (size_t)l * N_TYPES;

        ptl128_kernel<N_HID, 0, 1, 1><<<pgrid, 256, 0, stream>>>(
            hin, nidx, noff, kwl, kbl, nullptr, nullptr, KH);
        ptl128_kernel<N_HID, 0, 1, 0><<<pgrid, 256, 0, stream>>>(
            hin, nidx, noff, qwl, qbl, nullptr, nullptr, qb_);
        ptl128_kernel<N_HID, 0, 1, 1><<<pgrid, 256, 0, stream>>>(
            hin, nidx, noff, vwl, vbl, nullptr, nullptr, VH);

        hgt_edge_fused<<<fblocks, 256, 0, stream>>>(
            er_t, eoff, KH, VH, attl, msgl, pril, qb_);

        ptl128_kernel<N_HID, 1, 2, 0><<<pgrid, 256, 0, stream>>>(
            qb_, nidx, noff, awl, abl, skipl, hin, hout);
    }
}

// Round 14
// 1075.603 us; speedup vs baseline: 1.3295x; 1.1136x over previous
//
#include <hip/hip_runtime.h>
#include <hip/hip_fp16.h>
#include <math.h>

constexpr int N_TYPES = 4;
constexpr int N_REL   = 8;
constexpr int N_HEADS = 8;
constexpr int IN_DIM  = 256;
constexpr int N_HID   = 128;
constexpr int D_K     = 16;
constexpr int N_LAYERS= 2;
constexpr int NN      = 100000;
constexpr int NE      = 400000;
constexpr int NBLK    = (NN + 255) / 256;   // scan blocks

typedef _Float16 f16x8 __attribute__((ext_vector_type(8)));
typedef float    f32x4 __attribute__((ext_vector_type(4)));

__device__ __forceinline__ float gelu_f(float x) {
    const float c = 0.7978845608028654f; // sqrt(2/pi)
    float x3 = x * x * x;
    return 0.5f * x * (1.0f + tanhf(c * (x + 0.044715f * x3)));
}
__device__ __forceinline__ float sigmoid_f(float x) {
    return 1.0f / (1.0f + expf(-x));
}

// ---------------- bucketing: nodes by type, edges by target ----------------
__global__ __launch_bounds__(256) void count2_kernel(
    const int* __restrict__ ntype, const int* __restrict__ tgt,
    unsigned* ncnt, unsigned* tcnt)
{
    int i = blockIdx.x * 256 + threadIdx.x;
    int lane = threadIdx.x & 63;
    int t = (i < NN) ? ntype[i] : -1;
    #pragma unroll
    for (int tt = 0; tt < N_TYPES; tt++) {
        unsigned long long m = __ballot(t == tt);
        if (m != 0ull && lane == __ffsll((unsigned long long)m) - 1)
            atomicAdd(&ncnt[tt], (unsigned)__popcll(m));
    }
    if (i < NE) atomicAdd(&tcnt[tgt[i]], 1u);
}

__global__ void node_offsets_kernel(unsigned* c)
{
    // layout: ncnt[0:4] ncur[4:8] noff[8:13]
    unsigned a = 0;
    for (int t = 0; t < N_TYPES; t++) { c[8 + t] = a; c[4 + t] = a; a += c[t]; }
    c[8 + N_TYPES] = a;
}

// hierarchical exclusive scan over tcnt[NN] -> eoff[NN+1]
__global__ __launch_bounds__(256) void scan1_kernel(
    const unsigned* __restrict__ cnt, unsigned* __restrict__ eoff,
    unsigned* __restrict__ bsum)
{
    __shared__ unsigned sh[256];
    int i = blockIdx.x * 256 + threadIdx.x;
    unsigned v = (i < NN) ? cnt[i] : 0u;
    sh[threadIdx.x] = v;
    __syncthreads();
    for (int off = 1; off < 256; off <<= 1) {
        unsigned add = (threadIdx.x >= off) ? sh[threadIdx.x - off] : 0u;
        __syncthreads();
        sh[threadIdx.x] += add;
        __syncthreads();
    }
    if (i < NN) eoff[i] = sh[threadIdx.x] - v;      // block-local exclusive
    if (threadIdx.x == 255) bsum[blockIdx.x] = sh[255];
}

__global__ __launch_bounds__(512) void scan2_kernel(unsigned* __restrict__ bsum)
{
    __shared__ unsigned sh[512];
    int i = threadIdx.x;
    unsigned v = (i < NBLK) ? bsum[i] : 0u;
    sh[i] = v;
    __syncthreads();
    for (int off = 1; off < 512; off <<= 1) {
        unsigned add = (i >= off) ? sh[i - off] : 0u;
        __syncthreads();
        sh[i] += add;
        __syncthreads();
    }
    if (i < NBLK) bsum[i] = sh[i] - v;              // exclusive block offsets
}

__global__ __launch_bounds__(256) void scan3_kernel(
    unsigned* __restrict__ eoff, const unsigned* __restrict__ bsum,
    unsigned* __restrict__ ecur)
{
    int i = blockIdx.x * 256 + threadIdx.x;
    if (i < NN) {
        unsigned v = eoff[i] + bsum[blockIdx.x];
        eoff[i] = v;
        ecur[i] = v;
    }
    if (i == 0) eoff[NN] = (unsigned)NE;
}

__global__ __launch_bounds__(256) void scatter2_kernel(
    const int* __restrict__ ntype,
    const int* __restrict__ src, const int* __restrict__ tgt,
    const int* __restrict__ etype,
    unsigned* ncur, unsigned* ecur,
    int* __restrict__ nidx,
    int* __restrict__ er_t)            // packed (src<<3) | rel
{
    int i = blockIdx.x * 256 + threadIdx.x;
    int lane = threadIdx.x & 63;
    int t = (i < NN) ? ntype[i] : -1;
    // wave-aggregated slot assignment: 1 atomic per (wave, type) not per node
    #pragma unroll
    for (int tt = 0; tt < N_TYPES; tt++) {
        unsigned long long m = __ballot(t == tt);
        if (m == 0ull) continue;
        int leader = __ffsll((unsigned long long)m) - 1;
        unsigned base = 0;
        if (lane == leader) base = atomicAdd(&ncur[tt], (unsigned)__popcll(m));
        base = __shfl(base, leader, 64);
        if (t == tt) {
            unsigned rank = (unsigned)__popcll(m & ((1ull << lane) - 1ull));
            nidx[base + rank] = i;
        }
    }
    if (i < NE) {
        int tg = tgt[i];
        unsigned p = atomicAdd(&ecur[tg], 1u);   // 100K distinct addrs, low contention
        er_t[p] = (src[i] << 3) | etype[i];
    }
}

// ---------------- weight convert+transpose: W[4][128][128] f32 -> W^T fp16 --
__global__ __launch_bounds__(256) void cvt_wT_kernel(
    const float* __restrict__ W, __half* __restrict__ whT)
{
    int gid = blockIdx.x * 256 + threadIdx.x;
    constexpr int tot = 4 * 128 * 128;
    if (gid >= tot) return;
    int t = gid >> 14;                 // /(128*128)
    int rem = gid & 16383;
    int k = rem >> 7, n = rem & 127;
    whT[(((size_t)t * 128 + n) << 7) + k] = __float2half(W[gid]);
}

// ---------------- fp32 per-type linear (adapter), 128x128 tile, BK=32 ------
// MOUT fixed: tanh.  OH: 0 = fp32 out, 1 = fp16 out.
template<int DIN, int OH>
__global__ __launch_bounds__(256) void ptl128_kernel(
    const float* __restrict__ x,
    const int* __restrict__ nidx,
    const unsigned* __restrict__ noff,
    const float* __restrict__ W,     // [4, DIN, 128]
    const float* __restrict__ Bb,    // [4, 128]
    void* __restrict__ out)
{
    constexpr int BK = 32;
    const int t = blockIdx.y;
    const unsigned s0 = noff[t], s1 = noff[t + 1];
    const unsigned base = s0 + blockIdx.x * 128u;
    if (base >= s1) return;
    const int nrows = (int)min(128u, s1 - base);

    __shared__ __align__(16) float xs[BK][128];
    __shared__ __align__(16) float wsl[BK][128];
    __shared__ int nid[128];

    const int tid = threadIdx.x;
    if (tid < 128) nid[tid] = nidx[base + (unsigned)min(tid, nrows - 1)];
    __syncthreads();

    const int tx = tid & 15;
    const int ty = tid >> 4;
    const int row = tid & 127, kg = tid >> 7;

    float acc[8][8];
    #pragma unroll
    for (int m = 0; m < 8; m++)
        #pragma unroll
        for (int j = 0; j < 8; j++) acc[m][j] = 0.0f;

    const float* Wt = W + (size_t)t * DIN * 128;

    for (int k0 = 0; k0 < DIN; k0 += BK) {
        {
            const float* xp = x + (size_t)nid[row] * DIN + k0 + kg * 16;
            float4 a0 = ((const float4*)xp)[0];
            float4 a1 = ((const float4*)xp)[1];
            float4 a2 = ((const float4*)xp)[2];
            float4 a3 = ((const float4*)xp)[3];
            float v[16] = {a0.x, a0.y, a0.z, a0.w, a1.x, a1.y, a1.z, a1.w,
                           a2.x, a2.y, a2.z, a2.w, a3.x, a3.y, a3.z, a3.w};
            #pragma unroll
            for (int i = 0; i < 16; i++) xs[kg * 16 + i][row] = v[i];
        }
        {
            const float* wp = Wt + (size_t)k0 * 128 + tid * 16;
            #pragma unroll
            for (int i = 0; i < 4; i++)
                *(float4*)&wsl[0][tid * 16 + 4 * i] = ((const float4*)wp)[i];
        }
        __syncthreads();
        #pragma unroll 8
        for (int kk = 0; kk < BK; kk++) {
            float4 xa = *(float4*)&xs[kk][ty * 8];
            float4 xb = *(float4*)&xs[kk][ty * 8 + 4];
            float4 wa = *(float4*)&wsl[kk][tx * 8];
            float4 wb = *(float4*)&wsl[kk][tx * 8 + 4];
            float xv[8] = {xa.x, xa.y, xa.z, xa.w, xb.x, xb.y, xb.z, xb.w};
            float wv[8] = {wa.x, wa.y, wa.z, wa.w, wb.x, wb.y, wb.z, wb.w};
            #pragma unroll
            for (int m = 0; m < 8; m++)
                #pragma unroll
                for (int j = 0; j < 8; j++)
                    acc[m][j] += xv[m] * wv[j];
        }
        __syncthreads();
    }

    float bb[8];
    #pragma unroll
    for (int j = 0; j < 8; j++) bb[j] = Bb[t * 128 + tx * 8 + j];

    #pragma unroll
    for (int m = 0; m < 8; m++) {
        int rr = ty * 8 + m;
        if (rr < nrows) {
            int n = nid[rr];
            float o[8];
            #pragma unroll
            for (int j = 0; j < 8; j++) o[j] = tanhf(acc[m][j] + bb[j]);
            if (OH == 0) {
                float* op = (float*)out + (size_t)n * 128 + tx * 8;
                *(float4*)(op)     = make_float4(o[0], o[1], o[2], o[3]);
                *(float4*)(op + 4) = make_float4(o[4], o[5], o[6], o[7]);
            } else {
                __align__(16) __half hh[8];
                #pragma unroll
                for (int j = 0; j < 8; j++) hh[j] = __float2half(o[j]);
                __half* op = (__half*)out + (size_t)n * 128 + tx * 8;
                *(uint4*)op = *(uint4*)hh;
            }
        }
    }
}

// ---------------- fp16 MFMA per-type linear (layer GEMMs) ------------------
// 128x128 tile, 4 waves (2x2), 4x4 frags of mfma_f32_16x16x32_f16 (1 per frag
// per K-step — single-pass fp16, unlike R11's 3x bf16-split).
// A: lane holds X[row=lane&15][k=(lane>>4)*8+0..8); B: W^T staged [col][k].
// C/D: col=lane&15, row=(lane>>4)*4+i (R11-verified mapping, dtype-indep).
// MOUT: 1 = plain+bias, 2 = skip-mix with hprev.  OH: 0 = f32 out, 1 = f16.
template<int MOUT, int OH>
__global__ __launch_bounds__(256) void mfma_ptl_kernel(
    const __half* __restrict__ xh,      // [*][128] fp16 activations
    const int* __restrict__ nidx, const unsigned* __restrict__ noff,
    const __half* __restrict__ whT,     // [4][128(n)][128(k)] fp16
    const float* __restrict__ Bb,
    const float* __restrict__ skipv, const __half* __restrict__ hprev,
    void* __restrict__ out)
{
    constexpr int DIN = 128;
    const int t = blockIdx.y;
    const unsigned s0 = noff[t], s1 = noff[t + 1];
    const unsigned base = s0 + blockIdx.x * 128u;
    if (base >= s1) return;
    const int nrows = (int)min(128u, s1 - base);

    __shared__ __align__(16) ushort xsh[128][40];
    __shared__ __align__(16) ushort wsh[128][40];
    __shared__ int nid[128];

    const int tid = threadIdx.x;
    if (tid < 128) nid[tid] = nidx[base + (unsigned)min(tid, nrows - 1)];
    __syncthreads();

    const int lane = tid & 63;
    const int wave = tid >> 6;
    const int wr = wave >> 1, wc = wave & 1;   // 2x2 wave grid over 128x128
    const int lm = lane & 15, lk = lane >> 4;

    f32x4 acc[4][4];
    #pragma unroll
    for (int a = 0; a < 4; a++)
        #pragma unroll
        for (int b = 0; b < 4; b++)
            acc[a][b] = (f32x4){0.0f, 0.0f, 0.0f, 0.0f};

    const ushort* WT = (const ushort*)(whT + ((size_t)t << 14));
    const ushort* X  = (const ushort*)xh;

    const int srow = tid & 127, shalf = tid >> 7;
    const size_t xoff = (size_t)nid[srow] * DIN;

    for (int k0 = 0; k0 < DIN; k0 += 32) {
        {
            const ushort* ph = X + xoff + k0 + shalf * 16;
            *(uint4*)&xsh[srow][shalf * 16]     = *(const uint4*)ph;
            *(uint4*)&xsh[srow][shalf * 16 + 8] = *(const uint4*)(ph + 8);
            const ushort* qh = WT + ((size_t)srow << 7) + k0 + shalf * 16;
            *(uint4*)&wsh[srow][shalf * 16]     = *(const uint4*)qh;
            *(uint4*)&wsh[srow][shalf * 16 + 8] = *(const uint4*)(qh + 8);
        }
        __syncthreads();
        f16x8 ah[4];
        #pragma unroll
        for (int fm = 0; fm < 4; fm++)
            ah[fm] = *(const f16x8*)&xsh[wr * 64 + fm * 16 + lm][lk * 8];
        #pragma unroll
        for (int fn = 0; fn < 4; fn++) {
            f16x8 bh = *(const f16x8*)&wsh[wc * 64 + fn * 16 + lm][lk * 8];
            #pragma unroll
            for (int fm = 0; fm < 4; fm++)
                acc[fm][fn] = __builtin_amdgcn_mfma_f32_16x16x32_f16(
                    ah[fm], bh, acc[fm][fn], 0, 0, 0);
        }
        __syncthreads();
    }

    float alpha = 0.0f;
    if (MOUT == 2) alpha = sigmoid_f(skipv[t]);
    #pragma unroll
    for (int fn = 0; fn < 4; fn++) {
        const int dim = wc * 64 + fn * 16 + lm;
        const float bias = Bb[t * 128 + dim];
        #pragma unroll
        for (int fm = 0; fm < 4; fm++) {
            #pragma unroll
            for (int i = 0; i < 4; i++) {
                int rr = wr * 64 + fm * 16 + lk * 4 + i;
                if (rr < nrows) {
                    int n = nid[rr];
                    float o = acc[fm][fn][i] + bias;
                    if (MOUT == 2)
                        o = o * alpha +
                            __half2float(hprev[(size_t)n * 128 + dim]) * (1.0f - alpha);
                    if (OH == 0) ((float*)out)[(size_t)n * 128 + dim] = o;
                    else ((__half*)out)[(size_t)n * 128 + dim] = __float2half(o);
                }
            }
        }
    }
}

// ---------------- fused edge phase (R13 form; q/agg fp16, gelu fused) -------
__global__ __launch_bounds__(256) void hgt_edge_fused(
    const int* __restrict__ er_t,       // packed (src<<3)|rel, sorted by tgt
    const unsigned* __restrict__ eoff,  // [NN+1]
    const __half* __restrict__ kh,      // [NN][128] fp16
    const __half* __restrict__ vh,      // [NN][128] fp16
    const float* __restrict__ att,      // [8,8,16,16] layer slice
    const float* __restrict__ msg,      // [8,8,16,16] layer slice
    const float* __restrict__ pri,      // [8,8]
    __half* __restrict__ qagg)          // q in, gelu(agg) out (in-place)
{
    __shared__ float aq_lds[2][1024];
    __shared__ float pv_lds[2][1024];
    const int tid  = threadIdx.x;
    const int tsel = tid >> 7;
    const int li   = tid & 127;
    const int h    = li >> 4;
    const int j    = li & 15;
    const int l    = tid & 63;
    const int hb   = tid & 0x30;
    const int t    = blockIdx.x * 2 + tsel;
    if (t >= NN) return;

    const unsigned e0 = eoff[t];
    const unsigned e1 = eoff[t + 1];
    const int deg = (int)(e1 - e0);

    if (deg == 0) {
        qagg[(size_t)t * 128 + li] = __float2half(0.0f);
        return;
    }

    float* al = aq_lds[tsel];
    float* pl = pv_lds[tsel];

    #pragma unroll
    for (int r = 0; r < 8; r++) pl[r * 128 + li] = 0.0f;

    const float qo = __half2float(qagg[(size_t)t * 128 + li]);
    float qh[16];
    #pragma unroll
    for (int f = 0; f < 16; f++) qh[f] = __shfl(qo, hb + f, 64);

    int pkl = 0;
    if (l < 16 && e0 + (unsigned)l < e1) pkl = er_t[e0 + l];

    const int dc = min(deg, 16);
    unsigned mask = 0;
    for (int c = 0; c < dc; ++c) mask |= 1u << (__shfl(pkl, c, 64) & 7);
    for (unsigned e = e0 + 16; e < e1; ++e) mask |= 1u << (er_t[e] & 7);

    unsigned need = mask;
    while (need) {
        const int r = __ffs(need) - 1; need &= need - 1;
        const float* Ar = att + (((r * 8 + h) * 16 + j) * 16);
        float4 A0 = ((const float4*)Ar)[0];
        float4 A1 = ((const float4*)Ar)[1];
        float4 A2 = ((const float4*)Ar)[2];
        float4 A3 = ((const float4*)Ar)[3];
        float acc =
            A0.x*qh[0]  + A0.y*qh[1]  + A0.z*qh[2]  + A0.w*qh[3]  +
            A1.x*qh[4]  + A1.y*qh[5]  + A1.z*qh[6]  + A1.w*qh[7]  +
            A2.x*qh[8]  + A2.y*qh[9]  + A2.z*qh[10] + A2.w*qh[11] +
            A3.x*qh[12] + A3.y*qh[13] + A3.z*qh[14] + A3.w*qh[15];
        al[r * 128 + li] = acc * pri[r * 8 + h] * 0.25f;
    }

    float z = 0.0f;
    float* plp = pl + li;
    const float* alp = al + li;
    const __half* kb = kh + li;
    const __half* vb = vh + li;

    unsigned e = e0;
    for (; e + 4 <= e1; e += 4) {
        const int o = (int)(e - e0);
        int p0, p1, p2, p3;
        if (o + 3 < 16) {
            p0 = __shfl(pkl, o + 0, 64);
            p1 = __shfl(pkl, o + 1, 64);
            p2 = __shfl(pkl, o + 2, 64);
            p3 = __shfl(pkl, o + 3, 64);
        } else {
            p0 = er_t[e + 0]; p1 = er_t[e + 1];
            p2 = er_t[e + 2]; p3 = er_t[e + 3];
        }
        const int o0 = (p0 & ~7) << 4;
        const int o1 = (p1 & ~7) << 4;
        const int o2 = (p2 & ~7) << 4;
        const int o3 = (p3 & ~7) << 4;
        const float k0 = __half2float(kb[o0]); const float v0 = __half2float(vb[o0]);
        const float k1 = __half2float(kb[o1]); const float v1 = __half2float(vb[o1]);
        const float k2 = __half2float(kb[o2]); const float v2 = __half2float(vb[o2]);
        const float k3 = __half2float(kb[o3]); const float v3 = __half2float(vb[o3]);
        float s0 = k0 * alp[(p0 & 7) * 128];
        float s1 = k1 * alp[(p1 & 7) * 128];
        float s2 = k2 * alp[(p2 & 7) * 128];
        float s3 = k3 * alp[(p3 & 7) * 128];
        s0 += __shfl_xor(s0, 1); s1 += __shfl_xor(s1, 1);
        s2 += __shfl_xor(s2, 1); s3 += __shfl_xor(s3, 1);
        s0 += __shfl_xor(s0, 2); s1 += __shfl_xor(s1, 2);
        s2 += __shfl_xor(s2, 2); s3 += __shfl_xor(s3, 2);
        s0 += __shfl_xor(s0, 4); s1 += __shfl_xor(s1, 4);
        s2 += __shfl_xor(s2, 4); s3 += __shfl_xor(s3, 4);
        s0 += __shfl_xor(s0, 8); s1 += __shfl_xor(s1, 8);
        s2 += __shfl_xor(s2, 8); s3 += __shfl_xor(s3, 8);
        const float q0 = __expf(s0 - 8.0f);
        const float q1 = __expf(s1 - 8.0f);
        const float q2 = __expf(s2 - 8.0f);
        const float q3 = __expf(s3 - 8.0f);
        z += q0 + q1 + q2 + q3;
        plp[(p0 & 7) * 128] += q0 * v0;
        plp[(p1 & 7) * 128] += q1 * v1;
        plp[(p2 & 7) * 128] += q2 * v2;
        plp[(p3 & 7) * 128] += q3 * v3;
    }
    if (e + 2 <= e1) {
        const int o = (int)(e - e0);
        int p0, p1;
        if (o + 1 < 16) { p0 = __shfl(pkl, o, 64); p1 = __shfl(pkl, o + 1, 64); }
        else            { p0 = er_t[e]; p1 = er_t[e + 1]; }
        const int o0 = (p0 & ~7) << 4;
        const int o1 = (p1 & ~7) << 4;
        const float k0 = __half2float(kb[o0]); const float v0 = __half2float(vb[o0]);
        const float k1 = __half2float(kb[o1]); const float v1 = __half2float(vb[o1]);
        float s0 = k0 * alp[(p0 & 7) * 128];
        float s1 = k1 * alp[(p1 & 7) * 128];
        s0 += __shfl_xor(s0, 1); s1 += __shfl_xor(s1, 1);
        s0 += __shfl_xor(s0, 2); s1 += __shfl_xor(s1, 2);
        s0 += __shfl_xor(s0, 4); s1 += __shfl_xor(s1, 4);
        s0 += __shfl_xor(s0, 8); s1 += __shfl_xor(s1, 8);
        const float q0 = __expf(s0 - 8.0f);
        const float q1 = __expf(s1 - 8.0f);
        z += q0 + q1;
        plp[(p0 & 7) * 128] += q0 * v0;
        plp[(p1 & 7) * 128] += q1 * v1;
        e += 2;
    }
    if (e < e1) {
        const int o = (int)(e - e0);
        const int p0 = (o < 16) ? __shfl(pkl, o, 64) : er_t[e];
        const int o0 = (p0 & ~7) << 4;
        const float k0 = __half2float(kb[o0]); const float v0 = __half2float(vb[o0]);
        float s0 = k0 * alp[(p0 & 7) * 128];
        s0 += __shfl_xor(s0, 1);
        s0 += __shfl_xor(s0, 2);
        s0 += __shfl_xor(s0, 4);
        s0 += __shfl_xor(s0, 8);
        const float q0 = __expf(s0 - 8.0f);
        z += q0;
        plp[(p0 & 7) * 128] += q0 * v0;
    }

    float acc = 0.0f;
    for (int r = 0; r < 8; r++) {
        if (!((mask >> r) & 1)) continue;
        const float* Mr = msg + ((r * 8 + h) * 256) + j;
        const float* sb = pl + r * 128 + h * 16;
        #pragma unroll
        for (int d = 0; d < 16; d++)
            acc += sb[d] * Mr[d * 16];
    }
    // fused gelu (out-proj input), fp16 store
    qagg[(size_t)t * 128 + li] =
        __float2half(gelu_f(acc * __frcp_rn(z + 1e-9f)));
}

// ---------------- launch ----------------
extern "C" void kernel_launch(void* const* d_in, const int* in_sizes, int n_in,
                              void* d_out, int out_size, void* d_ws, size_t ws_size,
                              hipStream_t stream)
{
    const float* node_feature = (const float*)d_in[0];
    const int*   node_type    = (const int*)d_in[1];
    const int*   edge_index   = (const int*)d_in[2];
    const int*   edge_type    = (const int*)d_in[3];
    const float* adapt_w      = (const float*)d_in[4];
    const float* adapt_b      = (const float*)d_in[5];
    const float* k_w = (const float*)d_in[6];
    const float* k_b = (const float*)d_in[7];
    const float* q_w = (const float*)d_in[8];
    const float* q_b = (const float*)d_in[9];
    const float* v_w = (const float*)d_in[10];
    const float* v_b = (const float*)d_in[11];
    const float* a_w = (const float*)d_in[12];
    const float* a_b = (const float*)d_in[13];
    const float* rel_pri = (const float*)d_in[14];
    const float* rel_att = (const float*)d_in[15];
    const float* rel_msg = (const float*)d_in[16];
    const float* skip    = (const float*)d_in[17];

    const int* src = edge_index;
    const int* tgt = edge_index + NE;

    float* OUT = (float*)d_out;

    char* w = (char*)d_ws;
    auto alloc = [&](size_t bytes) -> void* {
        void* p = (void*)w;
        w += (bytes + 255) & ~(size_t)255;
        return p;
    };
    __half*   H0    = (__half*)alloc((size_t)NN * 128 * 2);
    __half*   H1    = (__half*)alloc((size_t)NN * 128 * 2);
    __half*   KH    = (__half*)alloc((size_t)NN * 128 * 2);
    __half*   VH    = (__half*)alloc((size_t)NN * 128 * 2);
    __half*   QA    = (__half*)alloc((size_t)NN * 128 * 2);
    __half*   WHT   = (__half*)alloc((size_t)8 * 4 * 128 * 128 * 2);
    int*      nidx  = (int*)alloc((size_t)NN * 4);
    int*      er_t  = (int*)alloc((size_t)NE * 4);
    unsigned* tcnt  = (unsigned*)alloc((size_t)NN * 4);
    unsigned* eoff  = (unsigned*)alloc((size_t)(NN + 1) * 4);
    unsigned* ecur  = (unsigned*)alloc((size_t)NN * 4);
    unsigned* bsum  = (unsigned*)alloc((size_t)NBLK * 4);
    unsigned* cnts  = (unsigned*)alloc(16 * 4);

    unsigned* ncnt = cnts;          // 4
    unsigned* ncur = cnts + 4;      // 4
    unsigned* noff = cnts + 8;      // 5

    hipMemsetAsync(cnts, 0, 16 * 4, stream);
    hipMemsetAsync(tcnt, 0, (size_t)NN * 4, stream);

    const int gblocks = (NE + 255) / 256;
    count2_kernel<<<gblocks, 256, 0, stream>>>(node_type, tgt, ncnt, tcnt);
    node_offsets_kernel<<<1, 1, 0, stream>>>(cnts);
    scan1_kernel<<<NBLK, 256, 0, stream>>>(tcnt, eoff, bsum);
    scan2_kernel<<<1, 512, 0, stream>>>(bsum);
    scan3_kernel<<<NBLK, 256, 0, stream>>>(eoff, bsum, ecur);
    scatter2_kernel<<<gblocks, 256, 0, stream>>>(node_type, src, tgt, edge_type,
                                                 ncur, ecur, nidx, er_t);

    // fp16-transpose the 8 layer weight tensors (once per call)
    {
        constexpr int wtot = 4 * 128 * 128;
        const int wblk = (wtot + 255) / 256;
        const float* Ws[8] = {
            k_w, q_w, v_w, a_w,
            k_w + (size_t)wtot, q_w + (size_t)wtot,
            v_w + (size_t)wtot, a_w + (size_t)wtot };
        for (int m = 0; m < 8; m++)
            cvt_wT_kernel<<<wblk, 256, 0, stream>>>(Ws[m], WHT + (size_t)m * wtot);
    }

    dim3 pgrid((NN + 127) / 128, N_TYPES);
    ptl128_kernel<IN_DIM, 1><<<pgrid, 256, 0, stream>>>(
        node_feature, nidx, noff, adapt_w, adapt_b, H0);

    const int fblocks = (NN + 1) / 2;
    const size_t wtot = (size_t)4 * 128 * 128;

    for (int l = 0; l < N_LAYERS; l++) {
        __half* hin = l ? H1 : H0;

        const __half* khT = WHT + (size_t)(l * 4 + 0) * wtot;
        const __half* qhT = WHT + (size_t)(l * 4 + 1) * wtot;
        const __half* vhT = WHT + (size_t)(l * 4 + 2) * wtot;
        const __half* ahT = WHT + (size_t)(l * 4 + 3) * wtot;

        const float* kbl = k_b + (size_t)l * N_TYPES * 128;
        const float* qbl = q_b + (size_t)l * N_TYPES * 128;
        const float* vbl = v_b + (size_t)l * N_TYPES * 128;
        const float* abl = a_b + (size_t)l * N_TYPES * 128;
        const float* pril = rel_pri + (size_t)l * N_REL * N_HEADS;
        const float* attl = rel_att + (size_t)l * N_REL * N_HEADS * D_K * D_K;
        const float* msgl = rel_msg + (size_t)l * N_REL * N_HEADS * D_K * D_K;
        const float* skipl = skip + (size_t)l * N_TYPES;

        mfma_ptl_kernel<1, 1><<<pgrid, 256, 0, stream>>>(
            hin, nidx, noff, khT, kbl, nullptr, nullptr, KH);
        mfma_ptl_kernel<1, 1><<<pgrid, 256, 0, stream>>>(
            hin, nidx, noff, qhT, qbl, nullptr, nullptr, QA);
        mfma_ptl_kernel<1, 1><<<pgrid, 256, 0, stream>>>(
            hin, nidx, noff, vhT, vbl, nullptr, nullptr, VH);

        hgt_edge_fused<<<fblocks, 256, 0, stream>>>(
            er_t, eoff, KH, VH, attl, msgl, pril, QA);

        if (l == 0)
            mfma_ptl_kernel<2, 1><<<pgrid, 256, 0, stream>>>(
                QA, nidx, noff, ahT, abl, skipl, hin, H1);
        else
            mfma_ptl_kernel<2, 0><<<pgrid, 256, 0, stream>>>(
                QA, nidx, noff, ahT, abl, skipl, hin, OUT);
    }
}

// Round 15
// 1024.465 us; speedup vs baseline: 1.3958x; 1.0499x over previous
//
#include <hip/hip_runtime.h>
#include <hip/hip_fp16.h>
#include <math.h>

constexpr int N_TYPES = 4;
constexpr int N_REL   = 8;
constexpr int N_HEADS = 8;
constexpr int IN_DIM  = 256;
constexpr int N_HID   = 128;
constexpr int D_K     = 16;
constexpr int N_LAYERS= 2;
constexpr int NN      = 100000;
constexpr int NE      = 400000;
constexpr int NBLK    = (NN + 255) / 256;   // scan blocks

typedef _Float16 f16x8 __attribute__((ext_vector_type(8)));
typedef float    f32x4 __attribute__((ext_vector_type(4)));

__device__ __forceinline__ float gelu_f(float x) {
    const float c = 0.7978845608028654f; // sqrt(2/pi)
    float x3 = x * x * x;
    return 0.5f * x * (1.0f + tanhf(c * (x + 0.044715f * x3)));
}
__device__ __forceinline__ float sigmoid_f(float x) {
    return 1.0f / (1.0f + expf(-x));
}

// ---------------- bucketing: nodes by type, edges by target ----------------
__global__ __launch_bounds__(256) void count2_kernel(
    const int* __restrict__ ntype, const int* __restrict__ tgt,
    unsigned* ncnt, unsigned* tcnt)
{
    int i = blockIdx.x * 256 + threadIdx.x;
    int lane = threadIdx.x & 63;
    int t = (i < NN) ? ntype[i] : -1;
    #pragma unroll
    for (int tt = 0; tt < N_TYPES; tt++) {
        unsigned long long m = __ballot(t == tt);
        if (m != 0ull && lane == __ffsll((unsigned long long)m) - 1)
            atomicAdd(&ncnt[tt], (unsigned)__popcll(m));
    }
    if (i < NE) atomicAdd(&tcnt[tgt[i]], 1u);
}

__global__ void node_offsets_kernel(unsigned* c)
{
    // layout: ncnt[0:4] ncur[4:8] noff[8:13]
    unsigned a = 0;
    for (int t = 0; t < N_TYPES; t++) { c[8 + t] = a; c[4 + t] = a; a += c[t]; }
    c[8 + N_TYPES] = a;
}

// hierarchical exclusive scan over tcnt[NN] -> eoff[NN+1]
__global__ __launch_bounds__(256) void scan1_kernel(
    const unsigned* __restrict__ cnt, unsigned* __restrict__ eoff,
    unsigned* __restrict__ bsum)
{
    __shared__ unsigned sh[256];
    int i = blockIdx.x * 256 + threadIdx.x;
    unsigned v = (i < NN) ? cnt[i] : 0u;
    sh[threadIdx.x] = v;
    __syncthreads();
    for (int off = 1; off < 256; off <<= 1) {
        unsigned add = (threadIdx.x >= off) ? sh[threadIdx.x - off] : 0u;
        __syncthreads();
        sh[threadIdx.x] += add;
        __syncthreads();
    }
    if (i < NN) eoff[i] = sh[threadIdx.x] - v;      // block-local exclusive
    if (threadIdx.x == 255) bsum[blockIdx.x] = sh[255];
}

__global__ __launch_bounds__(512) void scan2_kernel(unsigned* __restrict__ bsum)
{
    __shared__ unsigned sh[512];
    int i = threadIdx.x;
    unsigned v = (i < NBLK) ? bsum[i] : 0u;
    sh[i] = v;
    __syncthreads();
    for (int off = 1; off < 512; off <<= 1) {
        unsigned add = (i >= off) ? sh[i - off] : 0u;
        __syncthreads();
        sh[i] += add;
        __syncthreads();
    }
    if (i < NBLK) bsum[i] = sh[i] - v;              // exclusive block offsets
}

__global__ __launch_bounds__(256) void scan3_kernel(
    unsigned* __restrict__ eoff, const unsigned* __restrict__ bsum,
    unsigned* __restrict__ ecur)
{
    int i = blockIdx.x * 256 + threadIdx.x;
    if (i < NN) {
        unsigned v = eoff[i] + bsum[blockIdx.x];
        eoff[i] = v;
        ecur[i] = v;
    }
    if (i == 0) eoff[NN] = (unsigned)NE;
}

__global__ __launch_bounds__(256) void scatter2_kernel(
    const int* __restrict__ ntype,
    const int* __restrict__ src, const int* __restrict__ tgt,
    const int* __restrict__ etype,
    unsigned* ncur, unsigned* ecur,
    int* __restrict__ nidx,
    int* __restrict__ er_t)            // packed (src<<3) | rel
{
    int i = blockIdx.x * 256 + threadIdx.x;
    int lane = threadIdx.x & 63;
    int t = (i < NN) ? ntype[i] : -1;
    // wave-aggregated slot assignment: 1 atomic per (wave, type) not per node
    #pragma unroll
    for (int tt = 0; tt < N_TYPES; tt++) {
        unsigned long long m = __ballot(t == tt);
        if (m == 0ull) continue;
        int leader = __ffsll((unsigned long long)m) - 1;
        unsigned base = 0;
        if (lane == leader) base = atomicAdd(&ncur[tt], (unsigned)__popcll(m));
        base = __shfl(base, leader, 64);
        if (t == tt) {
            unsigned rank = (unsigned)__popcll(m & ((1ull << lane) - 1ull));
            nidx[base + rank] = i;
        }
    }
    if (i < NE) {
        int tg = tgt[i];
        unsigned p = atomicAdd(&ecur[tg], 1u);   // 100K distinct addrs, low contention
        er_t[p] = (src[i] << 3) | etype[i];
    }
}

// ---- weight convert+transpose: all 8 layer mats [2][4][128][128] -> W^T fp16
__global__ __launch_bounds__(256) void cvt_w_layers_kernel(
    const float* __restrict__ kw, const float* __restrict__ qw,
    const float* __restrict__ vw, const float* __restrict__ aw,
    __half* __restrict__ whT)          // [(l*4+m)][4][128(n)][128(k)]
{
    int gid = blockIdx.x * 256 + threadIdx.x;
    constexpr int per = 2 * 4 * 128 * 128;      // 131072 per tensor
    if (gid >= 4 * per) return;
    int m = gid >> 17;
    int rem = gid & (per - 1);
    const float* W = (m == 0) ? kw : (m == 1) ? qw : (m == 2) ? vw : aw;
    float val = W[rem];
    int l = rem >> 16;
    int r2 = rem & 65535;
    int t = r2 >> 14;
    int r3 = r2 & 16383;
    int k = r3 >> 7, n = r3 & 127;
    whT[((size_t)(l * 4 + m) << 16) + ((size_t)t << 14) + (n << 7) + k] =
        __float2half(val);
}

// adapter: W[4][256][128] -> W^T [4][128(n)][256(k)] fp16
__global__ __launch_bounds__(256) void cvt_wA_kernel(
    const float* __restrict__ W, __half* __restrict__ whT)
{
    int gid = blockIdx.x * 256 + threadIdx.x;
    if (gid >= 4 * 256 * 128) return;
    int t = gid >> 15;
    int rem = gid & 32767;
    int k = rem >> 7, n = rem & 127;
    whT[((size_t)t * 128 + n) * 256 + k] = __float2half(W[gid]);
}

// ---------------- fp16 MFMA per-type linear ------------------
// 128x128 tile, 4 waves (2x2), 4x4 frags of mfma_f32_16x16x32_f16.
// F32IN: x is fp32 (converted during staging).  MOUT: 0=tanh, 2=skip-mix.
// OH: 0 = f32 out, 1 = f16 out.
template<int DIN, int F32IN, int MOUT, int OH>
__global__ __launch_bounds__(256) void mfma_ptl_kernel(
    const void* __restrict__ x,
    const int* __restrict__ nidx, const unsigned* __restrict__ noff,
    const __half* __restrict__ whT,     // [4][128(n)][DIN(k)] fp16
    const float* __restrict__ Bb,
    const float* __restrict__ skipv, const __half* __restrict__ hprev,
    void* __restrict__ out)
{
    const int t = blockIdx.y;
    const unsigned s0 = noff[t], s1 = noff[t + 1];
    const unsigned base = s0 + blockIdx.x * 128u;
    if (base >= s1) return;
    const int nrows = (int)min(128u, s1 - base);

    __shared__ __align__(16) ushort xsh[128][40];
    __shared__ __align__(16) ushort wsh[128][40];
    __shared__ int nid[128];

    const int tid = threadIdx.x;
    if (tid < 128) nid[tid] = nidx[base + (unsigned)min(tid, nrows - 1)];
    __syncthreads();

    const int lane = tid & 63;
    const int wave = tid >> 6;
    const int wr = wave >> 1, wc = wave & 1;
    const int lm = lane & 15, lk = lane >> 4;

    f32x4 acc[4][4];
    #pragma unroll
    for (int a = 0; a < 4; a++)
        #pragma unroll
        for (int b = 0; b < 4; b++)
            acc[a][b] = (f32x4){0.0f, 0.0f, 0.0f, 0.0f};

    const ushort* WT = (const ushort*)whT + (size_t)t * 128 * DIN;
    const int srow = tid & 127, shalf = tid >> 7;
    const size_t xoff = (size_t)nid[srow] * DIN;

    for (int k0 = 0; k0 < DIN; k0 += 32) {
        if (F32IN) {
            const float* xp = (const float*)x + xoff + k0 + shalf * 16;
            float4 a0 = ((const float4*)xp)[0];
            float4 a1 = ((const float4*)xp)[1];
            float4 a2 = ((const float4*)xp)[2];
            float4 a3 = ((const float4*)xp)[3];
            float v[16] = {a0.x, a0.y, a0.z, a0.w, a1.x, a1.y, a1.z, a1.w,
                           a2.x, a2.y, a2.z, a2.w, a3.x, a3.y, a3.z, a3.w};
            __align__(16) __half hh[16];
            #pragma unroll
            for (int i = 0; i < 16; i++) hh[i] = __float2half(v[i]);
            *(uint4*)&xsh[srow][shalf * 16]     = ((uint4*)hh)[0];
            *(uint4*)&xsh[srow][shalf * 16 + 8] = ((uint4*)hh)[1];
        } else {
            const ushort* ph = (const ushort*)x + xoff + k0 + shalf * 16;
            *(uint4*)&xsh[srow][shalf * 16]     = *(const uint4*)ph;
            *(uint4*)&xsh[srow][shalf * 16 + 8] = *(const uint4*)(ph + 8);
        }
        {
            const ushort* qh = WT + (size_t)srow * DIN + k0 + shalf * 16;
            *(uint4*)&wsh[srow][shalf * 16]     = *(const uint4*)qh;
            *(uint4*)&wsh[srow][shalf * 16 + 8] = *(const uint4*)(qh + 8);
        }
        __syncthreads();
        f16x8 ah[4];
        #pragma unroll
        for (int fm = 0; fm < 4; fm++)
            ah[fm] = *(const f16x8*)&xsh[wr * 64 + fm * 16 + lm][lk * 8];
        #pragma unroll
        for (int fn = 0; fn < 4; fn++) {
            f16x8 bh = *(const f16x8*)&wsh[wc * 64 + fn * 16 + lm][lk * 8];
            #pragma unroll
            for (int fm = 0; fm < 4; fm++)
                acc[fm][fn] = __builtin_amdgcn_mfma_f32_16x16x32_f16(
                    ah[fm], bh, acc[fm][fn], 0, 0, 0);
        }
        __syncthreads();
    }

    float alpha = 0.0f;
    if (MOUT == 2) alpha = sigmoid_f(skipv[t]);
    #pragma unroll
    for (int fn = 0; fn < 4; fn++) {
        const int dim = wc * 64 + fn * 16 + lm;
        const float bias = Bb[t * 128 + dim];
        #pragma unroll
        for (int fm = 0; fm < 4; fm++) {
            #pragma unroll
            for (int i = 0; i < 4; i++) {
                int rr = wr * 64 + fm * 16 + lk * 4 + i;
                if (rr < nrows) {
                    int n = nid[rr];
                    float o = acc[fm][fn][i] + bias;
                    if (MOUT == 0) o = tanhf(o);
                    else if (MOUT == 2)
                        o = o * alpha +
                            __half2float(hprev[(size_t)n * 128 + dim]) * (1.0f - alpha);
                    if (OH == 0) ((float*)out)[(size_t)n * 128 + dim] = o;
                    else ((__half*)out)[(size_t)n * 128 + dim] = __float2half(o);
                }
            }
        }
    }
}

// ---------------- fused k/q/v MFMA (X tile LDS-resident, 3 weight passes) ---
__global__ __launch_bounds__(256) void mfma_kqv_kernel(
    const __half* __restrict__ xh,
    const int* __restrict__ nidx, const unsigned* __restrict__ noff,
    const __half* __restrict__ wTk, const float* __restrict__ bk, __half* __restrict__ ok,
    const __half* __restrict__ wTq, const float* __restrict__ bq, __half* __restrict__ oq,
    const __half* __restrict__ wTv, const float* __restrict__ bv, __half* __restrict__ ov)
{
    const int t = blockIdx.y;
    const unsigned s0 = noff[t], s1 = noff[t + 1];
    const unsigned base = s0 + blockIdx.x * 128u;
    if (base >= s1) return;
    const int nrows = (int)min(128u, s1 - base);

    __shared__ __align__(16) ushort xsh[128][136];   // full 128-k X tile
    __shared__ __align__(16) ushort wsh[128][40];
    __shared__ int nid[128];

    const int tid = threadIdx.x;
    if (tid < 128) nid[tid] = nidx[base + (unsigned)min(tid, nrows - 1)];
    __syncthreads();

    const int srow = tid & 127, shalf = tid >> 7;
    {
        // stage full X row-half (128 B) once
        const ushort* xp = (const ushort*)xh + (size_t)nid[srow] * 128 + shalf * 64;
        #pragma unroll
        for (int i = 0; i < 8; i++)
            *(uint4*)&xsh[srow][shalf * 64 + i * 8] = ((const uint4*)xp)[i];
    }

    const int lane = tid & 63;
    const int wave = tid >> 6;
    const int wr = wave >> 1, wc = wave & 1;
    const int lm = lane & 15, lk = lane >> 4;

    const ushort* WTs[3] = { (const ushort*)wTk + ((size_t)t << 14),
                             (const ushort*)wTq + ((size_t)t << 14),
                             (const ushort*)wTv + ((size_t)t << 14) };
    const float* Bs[3] = { bk, bq, bv };
    __half* Os[3] = { ok, oq, ov };

    #pragma unroll
    for (int w = 0; w < 3; w++) {
        f32x4 acc[4][4];
        #pragma unroll
        for (int a = 0; a < 4; a++)
            #pragma unroll
            for (int b = 0; b < 4; b++)
                acc[a][b] = (f32x4){0.0f, 0.0f, 0.0f, 0.0f};

        for (int k0 = 0; k0 < 128; k0 += 32) {
            __syncthreads();   // prior wsh readers done (and X staged, 1st iter)
            {
                const ushort* qh = WTs[w] + ((size_t)srow << 7) + k0 + shalf * 16;
                *(uint4*)&wsh[srow][shalf * 16]     = *(const uint4*)qh;
                *(uint4*)&wsh[srow][shalf * 16 + 8] = *(const uint4*)(qh + 8);
            }
            __syncthreads();
            f16x8 ah[4];
            #pragma unroll
            for (int fm = 0; fm < 4; fm++)
                ah[fm] = *(const f16x8*)&xsh[wr * 64 + fm * 16 + lm][k0 + lk * 8];
            #pragma unroll
            for (int fn = 0; fn < 4; fn++) {
                f16x8 bh = *(const f16x8*)&wsh[wc * 64 + fn * 16 + lm][lk * 8];
                #pragma unroll
                for (int fm = 0; fm < 4; fm++)
                    acc[fm][fn] = __builtin_amdgcn_mfma_f32_16x16x32_f16(
                        ah[fm], bh, acc[fm][fn], 0, 0, 0);
            }
        }
        // epilogue for this weight set
        #pragma unroll
        for (int fn = 0; fn < 4; fn++) {
            const int dim = wc * 64 + fn * 16 + lm;
            const float bias = Bs[w][t * 128 + dim];
            #pragma unroll
            for (int fm = 0; fm < 4; fm++) {
                #pragma unroll
                for (int i = 0; i < 4; i++) {
                    int rr = wr * 64 + fm * 16 + lk * 4 + i;
                    if (rr < nrows) {
                        int n = nid[rr];
                        Os[w][(size_t)n * 128 + dim] =
                            __float2half(acc[fm][fn][i] + bias);
                    }
                }
            }
        }
    }
}

// ---------------- fused edge phase (R14 form; q/agg fp16, gelu fused) -------
__global__ __launch_bounds__(256) void hgt_edge_fused(
    const int* __restrict__ er_t,       // packed (src<<3)|rel, sorted by tgt
    const unsigned* __restrict__ eoff,  // [NN+1]
    const __half* __restrict__ kh,      // [NN][128] fp16
    const __half* __restrict__ vh,      // [NN][128] fp16
    const float* __restrict__ att,      // [8,8,16,16] layer slice
    const float* __restrict__ msg,      // [8,8,16,16] layer slice
    const float* __restrict__ pri,      // [8,8]
    __half* __restrict__ qagg)          // q in, gelu(agg) out (in-place)
{
    __shared__ float aq_lds[2][1024];
    __shared__ float pv_lds[2][1024];
    const int tid  = threadIdx.x;
    const int tsel = tid >> 7;
    const int li   = tid & 127;
    const int h    = li >> 4;
    const int j    = li & 15;
    const int l    = tid & 63;
    const int hb   = tid & 0x30;
    const int t    = blockIdx.x * 2 + tsel;
    if (t >= NN) return;

    const unsigned e0 = eoff[t];
    const unsigned e1 = eoff[t + 1];
    const int deg = (int)(e1 - e0);

    if (deg == 0) {
        qagg[(size_t)t * 128 + li] = __float2half(0.0f);
        return;
    }

    float* al = aq_lds[tsel];
    float* pl = pv_lds[tsel];

    #pragma unroll
    for (int r = 0; r < 8; r++) pl[r * 128 + li] = 0.0f;

    const float qo = __half2float(qagg[(size_t)t * 128 + li]);
    float qh[16];
    #pragma unroll
    for (int f = 0; f < 16; f++) qh[f] = __shfl(qo, hb + f, 64);

    int pkl = 0;
    if (l < 16 && e0 + (unsigned)l < e1) pkl = er_t[e0 + l];

    const int dc = min(deg, 16);
    unsigned mask = 0;
    for (int c = 0; c < dc; ++c) mask |= 1u << (__shfl(pkl, c, 64) & 7);
    for (unsigned e = e0 + 16; e < e1; ++e) mask |= 1u << (er_t[e] & 7);

    unsigned need = mask;
    while (need) {
        const int r = __ffs(need) - 1; need &= need - 1;
        const float* Ar = att + (((r * 8 + h) * 16 + j) * 16);
        float4 A0 = ((const float4*)Ar)[0];
        float4 A1 = ((const float4*)Ar)[1];
        float4 A2 = ((const float4*)Ar)[2];
        float4 A3 = ((const float4*)Ar)[3];
        float acc =
            A0.x*qh[0]  + A0.y*qh[1]  + A0.z*qh[2]  + A0.w*qh[3]  +
            A1.x*qh[4]  + A1.y*qh[5]  + A1.z*qh[6]  + A1.w*qh[7]  +
            A2.x*qh[8]  + A2.y*qh[9]  + A2.z*qh[10] + A2.w*qh[11] +
            A3.x*qh[12] + A3.y*qh[13] + A3.z*qh[14] + A3.w*qh[15];
        al[r * 128 + li] = acc * pri[r * 8 + h] * 0.25f;
    }

    float z = 0.0f;
    float* plp = pl + li;
    const float* alp = al + li;
    const __half* kb = kh + li;
    const __half* vb = vh + li;

    unsigned e = e0;
    for (; e + 4 <= e1; e += 4) {
        const int o = (int)(e - e0);
        int p0, p1, p2, p3;
        if (o + 3 < 16) {
            p0 = __shfl(pkl, o + 0, 64);
            p1 = __shfl(pkl, o + 1, 64);
            p2 = __shfl(pkl, o + 2, 64);
            p3 = __shfl(pkl, o + 3, 64);
        } else {
            p0 = er_t[e + 0]; p1 = er_t[e + 1];
            p2 = er_t[e + 2]; p3 = er_t[e + 3];
        }
        const int o0 = (p0 & ~7) << 4;
        const int o1 = (p1 & ~7) << 4;
        const int o2 = (p2 & ~7) << 4;
        const int o3 = (p3 & ~7) << 4;
        const float k0 = __half2float(kb[o0]); const float v0 = __half2float(vb[o0]);
        const float k1 = __half2float(kb[o1]); const float v1 = __half2float(vb[o1]);
        const float k2 = __half2float(kb[o2]); const float v2 = __half2float(vb[o2]);
        const float k3 = __half2float(kb[o3]); const float v3 = __half2float(vb[o3]);
        float s0 = k0 * alp[(p0 & 7) * 128];
        float s1 = k1 * alp[(p1 & 7) * 128];
        float s2 = k2 * alp[(p2 & 7) * 128];
        float s3 = k3 * alp[(p3 & 7) * 128];
        s0 += __shfl_xor(s0, 1); s1 += __shfl_xor(s1, 1);
        s2 += __shfl_xor(s2, 1); s3 += __shfl_xor(s3, 1);
        s0 += __shfl_xor(s0, 2); s1 += __shfl_xor(s1, 2);
        s2 += __shfl_xor(s2, 2); s3 += __shfl_xor(s3, 2);
        s0 += __shfl_xor(s0, 4); s1 += __shfl_xor(s1, 4);
        s2 += __shfl_xor(s2, 4); s3 += __shfl_xor(s3, 4);
        s0 += __shfl_xor(s0, 8); s1 += __shfl_xor(s1, 8);
        s2 += __shfl_xor(s2, 8); s3 += __shfl_xor(s3, 8);
        const float q0 = __expf(s0 - 8.0f);
        const float q1 = __expf(s1 - 8.0f);
        const float q2 = __expf(s2 - 8.0f);
        const float q3 = __expf(s3 - 8.0f);
        z += q0 + q1 + q2 + q3;
        plp[(p0 & 7) * 128] += q0 * v0;
        plp[(p1 & 7) * 128] += q1 * v1;
        plp[(p2 & 7) * 128] += q2 * v2;
        plp[(p3 & 7) * 128] += q3 * v3;
    }
    if (e + 2 <= e1) {
        const int o = (int)(e - e0);
        int p0, p1;
        if (o + 1 < 16) { p0 = __shfl(pkl, o, 64); p1 = __shfl(pkl, o + 1, 64); }
        else            { p0 = er_t[e]; p1 = er_t[e + 1]; }
        const int o0 = (p0 & ~7) << 4;
        const int o1 = (p1 & ~7) << 4;
        const float k0 = __half2float(kb[o0]); const float v0 = __half2float(vb[o0]);
        const float k1 = __half2float(kb[o1]); const float v1 = __half2float(vb[o1]);
        float s0 = k0 * alp[(p0 & 7) * 128];
        float s1 = k1 * alp[(p1 & 7) * 128];
        s0 += __shfl_xor(s0, 1); s1 += __shfl_xor(s1, 1);
        s0 += __shfl_xor(s0, 2); s1 += __shfl_xor(s1, 2);
        s0 += __shfl_xor(s0, 4); s1 += __shfl_xor(s1, 4);
        s0 += __shfl_xor(s0, 8); s1 += __shfl_xor(s1, 8);
        const float q0 = __expf(s0 - 8.0f);
        const float q1 = __expf(s1 - 8.0f);
        z += q0 + q1;
        plp[(p0 & 7) * 128] += q0 * v0;
        plp[(p1 & 7) * 128] += q1 * v1;
        e += 2;
    }
    if (e < e1) {
        const int o = (int)(e - e0);
        const int p0 = (o < 16) ? __shfl(pkl, o, 64) : er_t[e];
        const int o0 = (p0 & ~7) << 4;
        const float k0 = __half2float(kb[o0]); const float v0 = __half2float(vb[o0]);
        float s0 = k0 * alp[(p0 & 7) * 128];
        s0 += __shfl_xor(s0, 1);
        s0 += __shfl_xor(s0, 2);
        s0 += __shfl_xor(s0, 4);
        s0 += __shfl_xor(s0, 8);
        const float q0 = __expf(s0 - 8.0f);
        z += q0;
        plp[(p0 & 7) * 128] += q0 * v0;
    }

    float acc = 0.0f;
    for (int r = 0; r < 8; r++) {
        if (!((mask >> r) & 1)) continue;
        const float* Mr = msg + ((r * 8 + h) * 256) + j;
        const float* sb = pl + r * 128 + h * 16;
        #pragma unroll
        for (int d = 0; d < 16; d++)
            acc += sb[d] * Mr[d * 16];
    }
    // fused gelu (out-proj input), fp16 store
    qagg[(size_t)t * 128 + li] =
        __float2half(gelu_f(acc * __frcp_rn(z + 1e-9f)));
}

// ---------------- launch ----------------
extern "C" void kernel_launch(void* const* d_in, const int* in_sizes, int n_in,
                              void* d_out, int out_size, void* d_ws, size_t ws_size,
                              hipStream_t stream)
{
    const float* node_feature = (const float*)d_in[0];
    const int*   node_type    = (const int*)d_in[1];
    const int*   edge_index   = (const int*)d_in[2];
    const int*   edge_type    = (const int*)d_in[3];
    const float* adapt_w      = (const float*)d_in[4];
    const float* adapt_b      = (const float*)d_in[5];
    const float* k_w = (const float*)d_in[6];
    const float* k_b = (const float*)d_in[7];
    const float* q_w = (const float*)d_in[8];
    const float* q_b = (const float*)d_in[9];
    const float* v_w = (const float*)d_in[10];
    const float* v_b = (const float*)d_in[11];
    const float* a_w = (const float*)d_in[12];
    const float* a_b = (const float*)d_in[13];
    const float* rel_pri = (const float*)d_in[14];
    const float* rel_att = (const float*)d_in[15];
    const float* rel_msg = (const float*)d_in[16];
    const float* skip    = (const float*)d_in[17];

    const int* src = edge_index;
    const int* tgt = edge_index + NE;

    float* OUT = (float*)d_out;

    char* w = (char*)d_ws;
    auto alloc = [&](size_t bytes) -> void* {
        void* p = (void*)w;
        w += (bytes + 255) & ~(size_t)255;
        return p;
    };
    __half*   H0    = (__half*)alloc((size_t)NN * 128 * 2);
    __half*   H1    = (__half*)alloc((size_t)NN * 128 * 2);
    __half*   KH    = (__half*)alloc((size_t)NN * 128 * 2);
    __half*   VH    = (__half*)alloc((size_t)NN * 128 * 2);
    __half*   QA    = (__half*)alloc((size_t)NN * 128 * 2);
    __half*   WHT   = (__half*)alloc((size_t)8 * 4 * 128 * 128 * 2);
    __half*   WAT   = (__half*)alloc((size_t)4 * 128 * 256 * 2);
    int*      nidx  = (int*)alloc((size_t)NN * 4);
    int*      er_t  = (int*)alloc((size_t)NE * 4);
    unsigned* tcnt  = (unsigned*)alloc((size_t)NN * 4);
    unsigned* eoff  = (unsigned*)alloc((size_t)(NN + 1) * 4);
    unsigned* ecur  = (unsigned*)alloc((size_t)NN * 4);
    unsigned* bsum  = (unsigned*)alloc((size_t)NBLK * 4);
    unsigned* cnts  = (unsigned*)alloc(16 * 4);

    unsigned* ncnt = cnts;          // 4
    unsigned* ncur = cnts + 4;      // 4
    unsigned* noff = cnts + 8;      // 5

    hipMemsetAsync(cnts, 0, 16 * 4, stream);
    hipMemsetAsync(tcnt, 0, (size_t)NN * 4, stream);

    const int gblocks = (NE + 255) / 256;
    count2_kernel<<<gblocks, 256, 0, stream>>>(node_type, tgt, ncnt, tcnt);
    node_offsets_kernel<<<1, 1, 0, stream>>>(cnts);
    scan1_kernel<<<NBLK, 256, 0, stream>>>(tcnt, eoff, bsum);
    scan2_kernel<<<1, 512, 0, stream>>>(bsum);
    scan3_kernel<<<NBLK, 256, 0, stream>>>(eoff, bsum, ecur);
    scatter2_kernel<<<gblocks, 256, 0, stream>>>(node_type, src, tgt, edge_type,
                                                 ncur, ecur, nidx, er_t);

    // weight conversions: 2 dispatches total
    cvt_w_layers_kernel<<<(4 * 2 * 4 * 128 * 128 + 255) / 256, 256, 0, stream>>>(
        k_w, q_w, v_w, a_w, WHT);
    cvt_wA_kernel<<<(4 * 256 * 128 + 255) / 256, 256, 0, stream>>>(adapt_w, WAT);

    dim3 pgrid((NN + 127) / 128, N_TYPES);
    // adapter: fp32 input staged+converted, fp16 MFMA, tanh, fp16 out
    mfma_ptl_kernel<IN_DIM, 1, 0, 1><<<pgrid, 256, 0, stream>>>(
        node_feature, nidx, noff, WAT, adapt_b, nullptr, nullptr, H0);

    const int fblocks = (NN + 1) / 2;
    const size_t wtot = (size_t)4 * 128 * 128;

    for (int l = 0; l < N_LAYERS; l++) {
        __half* hin = l ? H1 : H0;

        const __half* khT = WHT + (size_t)(l * 4 + 0) * wtot;
        const __half* qhT = WHT + (size_t)(l * 4 + 1) * wtot;
        const __half* vhT = WHT + (size_t)(l * 4 + 2) * wtot;
        const __half* ahT = WHT + (size_t)(l * 4 + 3) * wtot;

        const float* kbl = k_b + (size_t)l * N_TYPES * 128;
        const float* qbl = q_b + (size_t)l * N_TYPES * 128;
        const float* vbl = v_b + (size_t)l * N_TYPES * 128;
        const float* abl = a_b + (size_t)l * N_TYPES * 128;
        const float* pril = rel_pri + (size_t)l * N_REL * N_HEADS;
        const float* attl = rel_att + (size_t)l * N_REL * N_HEADS * D_K * D_K;
        const float* msgl = rel_msg + (size_t)l * N_REL * N_HEADS * D_K * D_K;
        const float* skipl = skip + (size_t)l * N_TYPES;

        mfma_kqv_kernel<<<pgrid, 256, 0, stream>>>(
            hin, nidx, noff,
            khT, kbl, KH,
            qhT, qbl, QA,
            vhT, vbl, VH);

        hgt_edge_fused<<<fblocks, 256, 0, stream>>>(
            er_t, eoff, KH, VH, attl, msgl, pril, QA);

        if (l == 0)
            mfma_ptl_kernel<N_HID, 0, 2, 1><<<pgrid, 256, 0, stream>>>(
                QA, nidx, noff, ahT, abl, skipl, H0, H1);
        else
            mfma_ptl_kernel<N_HID, 0, 2, 0><<<pgrid, 256, 0, stream>>>(
                QA, nidx, noff, ahT, abl, skipl, H1, OUT);
    }
}